// Round 4
// baseline (19600.104 us; speedup 1.0000x reference)
//
#include <hip/hip_runtime.h>
#include <hip/hip_bf16.h>

#define Bz 32
#define Sz 240
#define Hz 1024
#define Lz 8
#define NHEADS 16
#define NVOCAB 48
#define DHEAD 64

// lengths robustness: real lengths >= 120, so element[1]==0 (as int32) iff int64 LE.
__device__ __forceinline__ int get_len(const int* __restrict__ L, int b) {
  return (L[1] == 0) ? L[2 * b] : L[b];
}

// ---------------- embedding: argmax + gather + posenc ----------------
__global__ __launch_bounds__(256) void embed_kernel(
    const float* __restrict__ x, const float* __restrict__ w_emb,
    const float* __restrict__ p_emb, const int* __restrict__ lengths,
    float* __restrict__ z) {
  int bs = blockIdx.x;           // b*Sz + s
  int b = bs / Sz, s = bs % Sz;
  __shared__ int stok;
  if (threadIdx.x == 0) {
    const float* xr = x + (size_t)bs * NVOCAB;
    float best = xr[0]; int bi = 0;
    for (int j = 1; j < NVOCAB; ++j) {
      float v = xr[j];
      if (v > best) { best = v; bi = j; }   // strict > : first-occurrence tie-break
    }
    stok = bi;
  }
  __syncthreads();
  int tok = stok;
  float valid = (s < get_len(lengths, b)) ? 1.f : 0.f;
  const float* we = w_emb + (size_t)tok * Hz;
  const float* pe = p_emb + (size_t)s * Hz;
  float* zr = z + (size_t)bs * Hz;
  for (int h = threadIdx.x; h < Hz; h += blockDim.x)
    zr[h] = we[h] * valid + pe[h];
}

// ---------------- GEMM: C[M,N] = A[M,K] @ W[K,N] + bias, EPI=1 -> exact GELU ----------------
template <int EPI>
__global__ __launch_bounds__(256) void gemm_kernel(
    const float* __restrict__ A, const float* __restrict__ W,
    const float* __restrict__ bias, float* __restrict__ C,
    int M, int N, int K) {
  __shared__ float As[16][64];
  __shared__ float Ws[16][64];
  int tid = threadIdx.x;
  int tx = tid & 15, ty = tid >> 4;
  int row0 = blockIdx.y * 64, col0 = blockIdx.x * 64;
  float acc[4][4] = {};
  for (int k0 = 0; k0 < K; k0 += 16) {
    {
      int r = tid >> 2;              // 0..63
      int kk = (tid & 3) * 4;        // 0,4,8,12
      float4 a4 = *(const float4*)(A + (size_t)(row0 + r) * K + k0 + kk);
      As[kk + 0][r] = a4.x; As[kk + 1][r] = a4.y;
      As[kk + 2][r] = a4.z; As[kk + 3][r] = a4.w;
    }
    {
      int r = tid >> 4;              // 0..15
      int c = (tid & 15) * 4;        // 0..60
      float4 w4 = *(const float4*)(W + (size_t)(k0 + r) * N + col0 + c);
      Ws[r][c + 0] = w4.x; Ws[r][c + 1] = w4.y;
      Ws[r][c + 2] = w4.z; Ws[r][c + 3] = w4.w;
    }
    __syncthreads();
#pragma unroll
    for (int kk = 0; kk < 16; ++kk) {
      float a[4], w[4];
#pragma unroll
      for (int i = 0; i < 4; ++i) a[i] = As[kk][ty * 4 + i];
#pragma unroll
      for (int j = 0; j < 4; ++j) w[j] = Ws[kk][tx * 4 + j];
#pragma unroll
      for (int i = 0; i < 4; ++i)
#pragma unroll
        for (int j = 0; j < 4; ++j) acc[i][j] += a[i] * w[j];
    }
    __syncthreads();
  }
#pragma unroll
  for (int i = 0; i < 4; ++i) {
    int row = row0 + ty * 4 + i;
#pragma unroll
    for (int j = 0; j < 4; ++j) {
      int col = col0 + tx * 4 + j;
      float v = acc[i][j] + bias[col];
      if (EPI == 1) v = 0.5f * v * (1.f + erff(v * 0.70710678118654752f));
      C[(size_t)row * N + col] = v;
    }
  }
}

// ---------------- attention: one block per (qpos, head, b); writes into q in place ------------
__global__ __launch_bounds__(256) void attention_kernel(
    float* __restrict__ q, const float* __restrict__ k, const float* __restrict__ v,
    const int* __restrict__ lengths) {
  int qpos = blockIdx.x, head = blockIdx.y, b = blockIdx.z;
  int tid = threadIdx.x;
  __shared__ float qvec[DHEAD];
  __shared__ float scores[Sz];
  __shared__ float sred[256];
  __shared__ float part[256];

  size_t qoff = ((size_t)(b * Sz + qpos) * Hz) + head * DHEAD;
  if (tid < DHEAD) qvec[tid] = q[qoff + tid];
  __syncthreads();

  int n = qpos + 1;  // causal keys
  const float scale = 0.03125f;  // 1/sqrt(1024)
  float lmax = -1e30f;
  for (int kp = tid; kp < n; kp += 256) {
    const float* kr = k + ((size_t)(b * Sz + kp) * Hz) + head * DHEAD;
    float dot = 0.f;
#pragma unroll
    for (int d = 0; d < DHEAD; ++d) dot += qvec[d] * kr[d];
    dot *= scale;
    scores[kp] = dot;
    lmax = fmaxf(lmax, dot);
  }
  sred[tid] = lmax; __syncthreads();
  for (int off = 128; off > 0; off >>= 1) {
    if (tid < off) sred[tid] = fmaxf(sred[tid], sred[tid + off]);
    __syncthreads();
  }
  float smax = sred[0]; __syncthreads();

  float lsum = 0.f;
  for (int kp = tid; kp < n; kp += 256) {
    float e = expf(scores[kp] - smax);
    scores[kp] = e;
    lsum += e;
  }
  sred[tid] = lsum; __syncthreads();
  for (int off = 128; off > 0; off >>= 1) {
    if (tid < off) sred[tid] += sred[tid + off];
    __syncthreads();
  }
  float inv = 1.f / sred[0];

  // PV: 4 k-groups x 64 dims
  int d = tid & 63, g = tid >> 6;
  float acc = 0.f;
  for (int kp = g; kp < n; kp += 4)
    acc += scores[kp] * v[((size_t)(b * Sz + kp) * Hz) + head * DHEAD + d];
  part[tid] = acc;
  __syncthreads();
  if (tid < DHEAD) {
    float validf = (qpos < get_len(lengths, b)) ? 1.f : 0.f;
    float o = (part[tid] + part[64 + tid] + part[128 + tid] + part[192 + tid]) * inv;
    q[qoff + tid] = o * validf;
  }
}

// ---------------- residual + LayerNorm, in place on z ----------------
__global__ __launch_bounds__(256) void add_ln_kernel(
    float* __restrict__ z, const float* __restrict__ r,
    const float* __restrict__ gamma, const float* __restrict__ beta) {
  int bs = blockIdx.x, tid = threadIdx.x;
  size_t base = (size_t)bs * Hz;
  __shared__ float sred[256];
  float vals[4];
  float sum = 0.f;
#pragma unroll
  for (int j = 0; j < 4; ++j) {
    int h = tid + j * 256;
    vals[j] = z[base + h] + r[base + h];
    sum += vals[j];
  }
  sred[tid] = sum; __syncthreads();
  for (int off = 128; off > 0; off >>= 1) {
    if (tid < off) sred[tid] += sred[tid + off];
    __syncthreads();
  }
  float mean = sred[0] * (1.f / Hz); __syncthreads();
  float sq = 0.f;
#pragma unroll
  for (int j = 0; j < 4; ++j) { float d = vals[j] - mean; sq += d * d; }
  sred[tid] = sq; __syncthreads();
  for (int off = 128; off > 0; off >>= 1) {
    if (tid < off) sred[tid] += sred[tid + off];
    __syncthreads();
  }
  float rstd = rsqrtf(sred[0] * (1.f / Hz) + 1e-5f);
#pragma unroll
  for (int j = 0; j < 4; ++j) {
    int h = tid + j * 256;
    z[base + h] = (vals[j] - mean) * rstd * gamma[h] + beta[h];
  }
}

// ---------------- mean-pool + FC + softmax -> fp32 out ----------------
__global__ __launch_bounds__(256) void pool_kernel(
    const float* __restrict__ z, const float* __restrict__ Wfc,
    const float* __restrict__ bfc, float* __restrict__ out) {
  int b = blockIdx.x, tid = threadIdx.x;
  __shared__ float red[256][4];
  float acc[4] = {0.f, 0.f, 0.f, 0.f};
  for (int h = tid; h < Hz; h += 256) {
    float s = 0.f;
    for (int sp = 0; sp < Sz; ++sp) s += z[((size_t)(b * Sz + sp)) * Hz + h];
    float z2 = s * (1.f / Sz);
#pragma unroll
    for (int c = 0; c < 4; ++c) acc[c] += z2 * Wfc[h * 4 + c];
  }
#pragma unroll
  for (int c = 0; c < 4; ++c) red[tid][c] = acc[c];
  __syncthreads();
  for (int off = 128; off > 0; off >>= 1) {
    if (tid < off)
#pragma unroll
      for (int c = 0; c < 4; ++c) red[tid][c] += red[tid + off][c];
    __syncthreads();
  }
  if (tid == 0) {
    float lg[4], m = -1e30f;
#pragma unroll
    for (int c = 0; c < 4; ++c) { lg[c] = red[0][c] + bfc[c]; m = fmaxf(m, lg[c]); }
    float s = 0.f;
#pragma unroll
    for (int c = 0; c < 4; ++c) { lg[c] = expf(lg[c] - m); s += lg[c]; }
    float inv = 1.f / s;
#pragma unroll
    for (int c = 0; c < 4; ++c) out[b * 4 + c] = lg[c] * inv;
  }
}

extern "C" void kernel_launch(void* const* d_in, const int* in_sizes, int n_in,
                              void* d_out, int out_size, void* d_ws, size_t ws_size,
                              hipStream_t stream) {
  const float* x     = (const float*)d_in[0];
  const float* w_emb = (const float*)d_in[1];
  const float* p_emb = (const float*)d_in[2];
  const float* Wq = (const float*)d_in[3];
  const float* bq = (const float*)d_in[4];
  const float* Wk = (const float*)d_in[5];
  const float* bk = (const float*)d_in[6];
  const float* Wv = (const float*)d_in[7];
  const float* bv = (const float*)d_in[8];
  const float* W1 = (const float*)d_in[9];
  const float* b1 = (const float*)d_in[10];
  const float* W2 = (const float*)d_in[11];
  const float* b2 = (const float*)d_in[12];
  const float* ln1s = (const float*)d_in[13];
  const float* ln1b = (const float*)d_in[14];
  const float* ln2s = (const float*)d_in[15];
  const float* ln2b = (const float*)d_in[16];
  const float* Wfc  = (const float*)d_in[17];
  const float* bfc  = (const float*)d_in[18];
  const int* lengths = (const int*)d_in[19];
  float* out = (float*)d_out;

  const size_t BSH = (size_t)Bz * Sz * Hz;
  float* z  = (float*)d_ws;
  float* qb = z + BSH;
  float* kb = qb + BSH;
  float* vb = kb + BSH;

  const int M = Bz * Sz;  // 7680
  dim3 ggrid(Hz / 64, M / 64);  // (16, 120)

  embed_kernel<<<Bz * Sz, 256, 0, stream>>>(x, w_emb, p_emb, lengths, z);
  for (int i = 0; i < Lz; ++i) {
    size_t wo = (size_t)i * Hz * Hz, bo = (size_t)i * Hz;
    gemm_kernel<0><<<ggrid, 256, 0, stream>>>(z, Wq + wo, bq + bo, qb, M, Hz, Hz);
    gemm_kernel<0><<<ggrid, 256, 0, stream>>>(z, Wk + wo, bk + bo, kb, M, Hz, Hz);
    gemm_kernel<0><<<ggrid, 256, 0, stream>>>(z, Wv + wo, bv + bo, vb, M, Hz, Hz);
    attention_kernel<<<dim3(Sz, NHEADS, Bz), 256, 0, stream>>>(qb, kb, vb, lengths);
    add_ln_kernel<<<Bz * Sz, 256, 0, stream>>>(z, qb, ln1s + bo, ln1b + bo);
    gemm_kernel<1><<<ggrid, 256, 0, stream>>>(z, W1 + wo, b1 + bo, kb, M, Hz, Hz);
    gemm_kernel<0><<<ggrid, 256, 0, stream>>>(kb, W2 + wo, b2 + bo, vb, M, Hz, Hz);
    add_ln_kernel<<<Bz * Sz, 256, 0, stream>>>(z, vb, ln2s + bo, ln2b + bo);
  }
  pool_kernel<<<Bz, 256, 0, stream>>>(z, Wfc, bfc, out);
}

// Round 5
// 4594.548 us; speedup vs baseline: 4.2659x; 4.2659x over previous
//
#include <hip/hip_runtime.h>
#include <hip/hip_bf16.h>

#define Bz 32
#define Sz 240
#define Hz 1024
#define Lz 8
#define NHEADS 16
#define NVOCAB 48
#define DHEAD 64

typedef unsigned short u16;
typedef unsigned int u32;
typedef __attribute__((ext_vector_type(8))) short short8v;
typedef __attribute__((ext_vector_type(4))) float floatx4;

__device__ __forceinline__ int get_len(const int* __restrict__ L, int b) {
  return (L[1] == 0) ? L[2 * b] : L[b];   // int64 vs int32 robustness
}
__device__ __forceinline__ u16 f2bf(float f) {  // RNE fp32->bf16
  u32 u = __float_as_uint(f);
  return (u16)((u + 0x7FFFu + ((u >> 16) & 1u)) >> 16);
}
__device__ __forceinline__ float bf2f(u16 s) {
  return __uint_as_float(((u32)s) << 16);
}

// ---------------- embedding: argmax + gather + posenc (fp32 z) ----------------
__global__ __launch_bounds__(256) void embed_kernel(
    const float* __restrict__ x, const float* __restrict__ w_emb,
    const float* __restrict__ p_emb, const int* __restrict__ lengths,
    float* __restrict__ z) {
  int bs = blockIdx.x;
  int b = bs / Sz, s = bs % Sz;
  __shared__ int stok;
  if (threadIdx.x == 0) {
    const float* xr = x + (size_t)bs * NVOCAB;
    float best = xr[0]; int bi = 0;
    for (int j = 1; j < NVOCAB; ++j) {
      float v = xr[j];
      if (v > best) { best = v; bi = j; }
    }
    stok = bi;
  }
  __syncthreads();
  int tok = stok;
  float valid = (s < get_len(lengths, b)) ? 1.f : 0.f;
  const float* we = w_emb + (size_t)tok * Hz;
  const float* pe = p_emb + (size_t)s * Hz;
  float* zr = z + (size_t)bs * Hz;
  for (int h = threadIdx.x; h < Hz; h += blockDim.x)
    zr[h] = we[h] * valid + pe[h];
}

// ---------------- weight convert+transpose: fp32 W[K][N] -> bf16 Wt[N][K] ----------------
__global__ __launch_bounds__(256) void wconv_kernel(
    const float* __restrict__ W, u16* __restrict__ wt) {
  __shared__ u16 T[32][33];
  int bi = blockIdx.y, bj = blockIdx.x;       // k-tile, n-tile
  int r = threadIdx.x >> 3, c4 = (threadIdx.x & 7) * 4;
  float4 w4 = *(const float4*)(W + (size_t)(bi * 32 + r) * Hz + bj * 32 + c4);
  T[r][c4 + 0] = f2bf(w4.x); T[r][c4 + 1] = f2bf(w4.y);
  T[r][c4 + 2] = f2bf(w4.z); T[r][c4 + 3] = f2bf(w4.w);
  __syncthreads();
  u32 lo = (u32)T[c4 + 0][r] | ((u32)T[c4 + 1][r] << 16);
  u32 hi = (u32)T[c4 + 2][r] | ((u32)T[c4 + 3][r] << 16);
  uint2 val; val.x = lo; val.y = hi;
  *(uint2*)(wt + (size_t)(bj * 32 + r) * Hz + bi * 32 + c4) = val;
}

// ---------------- MFMA GEMM: C[7680,1024] = A(fp32) @ Wt^T(bf16) + bias ----------------
// 128x128 tile, BK=32, 4 waves (2x2), per-wave 64x64 via 4x4 frags of 16x16x32.
// LDS fragment order: [sub(8)][kchunk(4)][m/col(16)][kk(8)] -> all frag reads sequential b128.
template <bool OUTBF16, bool GELU>
__global__ __launch_bounds__(256) void gemm_mfma(
    const float* __restrict__ A, const u16* __restrict__ Wt,
    const float* __restrict__ bias, void* __restrict__ Cv) {
  __shared__ u16 As[4096];
  __shared__ u16 Bs[4096];
  int tid = threadIdx.x;
  int row0 = blockIdx.y * 128, col0 = blockIdx.x * 128;
  int w = tid >> 6, lane = tid & 63;
  int wr = w >> 1, wc = w & 1;
  floatx4 acc[4][4] = {};

  int r = tid >> 1, kh = tid & 1;             // staging: row/col r, k-half
  const float* aptr = A + (size_t)(row0 + r) * Hz + kh * 16;
  const u16* bptr = Wt + (size_t)(col0 + r) * Hz + kh * 16;
  int wbase = (r >> 4) * 512 + kh * 256 + (r & 15) * 8;  // shorts
  int afrag_off[4], bfrag_off[4];
#pragma unroll
  for (int i = 0; i < 4; ++i) {
    afrag_off[i] = (wr * 4 + i) * 512 + (lane >> 4) * 128 + (lane & 15) * 8;
    bfrag_off[i] = (wc * 4 + i) * 512 + (lane >> 4) * 128 + (lane & 15) * 8;
  }

  for (int k0 = 0; k0 < Hz; k0 += 32) {
    float4 a0 = *(const float4*)(aptr + k0);
    float4 a1 = *(const float4*)(aptr + k0 + 4);
    float4 a2 = *(const float4*)(aptr + k0 + 8);
    float4 a3 = *(const float4*)(aptr + k0 + 12);
    uint4 b01 = *(const uint4*)(bptr + k0);
    uint4 b23 = *(const uint4*)(bptr + k0 + 8);
    uint4 apk0, apk1;
    apk0.x = (u32)f2bf(a0.x) | ((u32)f2bf(a0.y) << 16);
    apk0.y = (u32)f2bf(a0.z) | ((u32)f2bf(a0.w) << 16);
    apk0.z = (u32)f2bf(a1.x) | ((u32)f2bf(a1.y) << 16);
    apk0.w = (u32)f2bf(a1.z) | ((u32)f2bf(a1.w) << 16);
    apk1.x = (u32)f2bf(a2.x) | ((u32)f2bf(a2.y) << 16);
    apk1.y = (u32)f2bf(a2.z) | ((u32)f2bf(a2.w) << 16);
    apk1.z = (u32)f2bf(a3.x) | ((u32)f2bf(a3.y) << 16);
    apk1.w = (u32)f2bf(a3.z) | ((u32)f2bf(a3.w) << 16);
    *(uint4*)(As + wbase) = apk0;
    *(uint4*)(As + wbase + 128) = apk1;
    *(uint4*)(Bs + wbase) = b01;
    *(uint4*)(Bs + wbase + 128) = b23;
    __syncthreads();
    short8v af[4], bf[4];
#pragma unroll
    for (int i = 0; i < 4; ++i) af[i] = *(const short8v*)(As + afrag_off[i]);
#pragma unroll
    for (int i = 0; i < 4; ++i) bf[i] = *(const short8v*)(Bs + bfrag_off[i]);
#pragma unroll
    for (int mi = 0; mi < 4; ++mi)
#pragma unroll
      for (int ni = 0; ni < 4; ++ni)
        acc[mi][ni] = __builtin_amdgcn_mfma_f32_16x16x32_bf16(
            af[mi], bf[ni], acc[mi][ni], 0, 0, 0);
    __syncthreads();
  }

  int rowbase = row0 + wr * 64, colbase = col0 + wc * 64;
#pragma unroll
  for (int ni = 0; ni < 4; ++ni) {
    int col = colbase + ni * 16 + (lane & 15);
    float bcol = bias[col];
#pragma unroll
    for (int mi = 0; mi < 4; ++mi) {
      int rtop = rowbase + mi * 16 + (lane >> 4) * 4;
#pragma unroll
      for (int reg = 0; reg < 4; ++reg) {
        float vv = acc[mi][ni][reg] + bcol;
        if (GELU) vv = 0.5f * vv * (1.f + erff(vv * 0.70710678118654752f));
        if (OUTBF16)
          ((u16*)Cv)[(size_t)(rtop + reg) * Hz + col] = f2bf(vv);
        else
          ((float*)Cv)[(size_t)(rtop + reg) * Hz + col] = vv;
      }
    }
  }
}

// ---------------- attention: one block per (b,head), 512 thr = 8 waves ----------------
// K^T d-pair-packed in LDS; scores: lane=key, 2 rows/pass; softmax per-wave shfl;
// normalized P in LDS; PV: lane=dim, V read from global (bf16, L2-resident).
__global__ __launch_bounds__(512) void attention_kernel(
    const u16* __restrict__ q, const u16* __restrict__ k,
    const u16* __restrict__ v, const int* __restrict__ lengths,
    float* __restrict__ out) {
  __shared__ u32 K2s[32][241];
  __shared__ float qrowbuf[8][128];
  __shared__ float pbuf[8][2][240];
  int h = blockIdx.x & 15, b = blockIdx.x >> 4;
  int tid = threadIdx.x;
  const size_t base = ((size_t)b * Sz) * Hz + h * DHEAD;

  for (int idx = tid; idx < Sz * 32; idx += 512) {
    int j = idx >> 5, d2 = idx & 31;
    K2s[d2][j] = *(const u32*)(k + base + (size_t)j * Hz + 2 * d2);
  }
  __syncthreads();

  int w = tid >> 6, lane = tid & 63;
  int len_b = get_len(lengths, b);

  for (int i = 0; i < 15; ++i) {
    int r1 = w + 16 * i, r2 = r1 + 8;
    // stage q rows (scaled by 1/sqrt(H)=0.03125), lanes<32 -> r1, lanes>=32 -> r2
    {
      int rr = (lane < 32) ? r1 : r2;
      int dd = lane & 31;
      u32 qq = *(const u32*)(q + base + (size_t)rr * Hz + 2 * dd);
      float2 qv;
      qv.x = __uint_as_float(qq << 16) * 0.03125f;
      qv.y = __uint_as_float(qq & 0xFFFF0000u) * 0.03125f;
      *(float2*)&qrowbuf[w][((lane < 32) ? 0 : 64) + 2 * dd] = qv;
    }
    __asm__ volatile("s_waitcnt lgkmcnt(0)" ::: "memory");

    // scores for both rows: lane handles keys lane+64t
    float s1[4] = {0.f, 0.f, 0.f, 0.f};
    float s2[4] = {0.f, 0.f, 0.f, 0.f};
    for (int d2 = 0; d2 < 32; ++d2) {
      float2 qa = *(const float2*)&qrowbuf[w][2 * d2];
      float2 qb = *(const float2*)&qrowbuf[w][64 + 2 * d2];
#pragma unroll
      for (int t = 0; t < 4; ++t) {
        int key = lane + 64 * t;
        u32 kk = K2s[d2][(key < 240) ? key : 240];
        float k0 = __uint_as_float(kk << 16);
        float k1 = __uint_as_float(kk & 0xFFFF0000u);
        s1[t] += qa.x * k0 + qa.y * k1;
        s2[t] += qb.x * k0 + qb.y * k1;
      }
    }
    // softmax per row (wave-local)
#pragma unroll
    for (int t = 0; t < 4; ++t) {
      int key = lane + 64 * t;
      if (key > r1) s1[t] = -1e30f;
      if (key > r2) s2[t] = -1e30f;
    }
    float m1 = fmaxf(fmaxf(s1[0], s1[1]), fmaxf(s1[2], s1[3]));
    float m2 = fmaxf(fmaxf(s2[0], s2[1]), fmaxf(s2[2], s2[3]));
    for (int off = 32; off > 0; off >>= 1) {
      m1 = fmaxf(m1, __shfl_xor(m1, off));
      m2 = fmaxf(m2, __shfl_xor(m2, off));
    }
    float l1 = 0.f, l2 = 0.f;
#pragma unroll
    for (int t = 0; t < 4; ++t) {
      s1[t] = __expf(s1[t] - m1); l1 += s1[t];
      s2[t] = __expf(s2[t] - m2); l2 += s2[t];
    }
    for (int off = 32; off > 0; off >>= 1) {
      l1 += __shfl_xor(l1, off);
      l2 += __shfl_xor(l2, off);
    }
    float inv1 = 1.f / l1, inv2 = 1.f / l2;
#pragma unroll
    for (int t = 0; t < 4; ++t) {
      int key = lane + 64 * t;
      if (key < 240) {
        pbuf[w][0][key] = s1[t] * inv1;
        pbuf[w][1][key] = s2[t] * inv2;
      }
    }
    __asm__ volatile("s_waitcnt lgkmcnt(0)" ::: "memory");

    // PV: lane = dim d; keys 0..r2 (p for key>r1 is 0 in slot 0)
    float acc1 = 0.f, acc2 = 0.f;
    const u16* vp = v + base + lane;
    int j2 = 0;
    for (; j2 + 1 <= r2; j2 += 2) {
      float2 p1 = *(const float2*)&pbuf[w][0][j2];
      float2 p2 = *(const float2*)&pbuf[w][1][j2];
      float va = bf2f(vp[(size_t)j2 * Hz]);
      float vb = bf2f(vp[(size_t)(j2 + 1) * Hz]);
      acc1 += p1.x * va + p1.y * vb;
      acc2 += p2.x * va + p2.y * vb;
    }
    if (j2 == r2) {  // odd count tail
      float va = bf2f(vp[(size_t)r2 * Hz]);
      acc1 += pbuf[w][0][r2] * va;
      acc2 += pbuf[w][1][r2] * va;
    }
    float v1 = (r1 < len_b) ? 1.f : 0.f;
    float v2 = (r2 < len_b) ? 1.f : 0.f;
    out[base + (size_t)r1 * Hz + lane] = acc1 * v1;
    out[base + (size_t)r2 * Hz + lane] = acc2 * v2;
    __syncthreads();  // keep waves roughly in phase; also guards pbuf reuse
  }
}

// ---------------- residual + LayerNorm, in place on z ----------------
__global__ __launch_bounds__(256) void add_ln_kernel(
    float* __restrict__ z, const float* __restrict__ r,
    const float* __restrict__ gamma, const float* __restrict__ beta) {
  int bs = blockIdx.x, tid = threadIdx.x;
  size_t base = (size_t)bs * Hz;
  __shared__ float sred[256];
  float vals[4];
  float sum = 0.f;
#pragma unroll
  for (int j = 0; j < 4; ++j) {
    int hh = tid + j * 256;
    vals[j] = z[base + hh] + r[base + hh];
    sum += vals[j];
  }
  sred[tid] = sum; __syncthreads();
  for (int off = 128; off > 0; off >>= 1) {
    if (tid < off) sred[tid] += sred[tid + off];
    __syncthreads();
  }
  float mean = sred[0] * (1.f / Hz); __syncthreads();
  float sq = 0.f;
#pragma unroll
  for (int j = 0; j < 4; ++j) { float d = vals[j] - mean; sq += d * d; }
  sred[tid] = sq; __syncthreads();
  for (int off = 128; off > 0; off >>= 1) {
    if (tid < off) sred[tid] += sred[tid + off];
    __syncthreads();
  }
  float rstd = rsqrtf(sred[0] * (1.f / Hz) + 1e-5f);
#pragma unroll
  for (int j = 0; j < 4; ++j) {
    int hh = tid + j * 256;
    z[base + hh] = (vals[j] - mean) * rstd * gamma[hh] + beta[hh];
  }
}

// ---------------- mean-pool + FC + softmax -> fp32 out ----------------
__global__ __launch_bounds__(256) void pool_kernel(
    const float* __restrict__ z, const float* __restrict__ Wfc,
    const float* __restrict__ bfc, float* __restrict__ out) {
  int b = blockIdx.x, tid = threadIdx.x;
  __shared__ float red[256][4];
  float acc[4] = {0.f, 0.f, 0.f, 0.f};
  for (int hh = tid; hh < Hz; hh += 256) {
    float s = 0.f;
    for (int sp = 0; sp < Sz; ++sp) s += z[((size_t)(b * Sz + sp)) * Hz + hh];
    float z2 = s * (1.f / Sz);
#pragma unroll
    for (int c = 0; c < 4; ++c) acc[c] += z2 * Wfc[hh * 4 + c];
  }
#pragma unroll
  for (int c = 0; c < 4; ++c) red[tid][c] = acc[c];
  __syncthreads();
  for (int off = 128; off > 0; off >>= 1) {
    if (tid < off)
#pragma unroll
      for (int c = 0; c < 4; ++c) red[tid][c] += red[tid + off][c];
    __syncthreads();
  }
  if (tid == 0) {
    float lg[4], m = -1e30f;
#pragma unroll
    for (int c = 0; c < 4; ++c) { lg[c] = red[0][c] + bfc[c]; m = fmaxf(m, lg[c]); }
    float s = 0.f;
#pragma unroll
    for (int c = 0; c < 4; ++c) { lg[c] = expf(lg[c] - m); s += lg[c]; }
    float inv = 1.f / s;
#pragma unroll
    for (int c = 0; c < 4; ++c) out[b * 4 + c] = lg[c] * inv;
  }
}

extern "C" void kernel_launch(void* const* d_in, const int* in_sizes, int n_in,
                              void* d_out, int out_size, void* d_ws, size_t ws_size,
                              hipStream_t stream) {
  const float* x     = (const float*)d_in[0];
  const float* w_emb = (const float*)d_in[1];
  const float* p_emb = (const float*)d_in[2];
  const float* Wq = (const float*)d_in[3];
  const float* bq = (const float*)d_in[4];
  const float* Wk = (const float*)d_in[5];
  const float* bk = (const float*)d_in[6];
  const float* Wv = (const float*)d_in[7];
  const float* bv = (const float*)d_in[8];
  const float* W1 = (const float*)d_in[9];
  const float* b1 = (const float*)d_in[10];
  const float* W2 = (const float*)d_in[11];
  const float* b2 = (const float*)d_in[12];
  const float* ln1s = (const float*)d_in[13];
  const float* ln1b = (const float*)d_in[14];
  const float* ln2s = (const float*)d_in[15];
  const float* ln2b = (const float*)d_in[16];
  const float* Wfc  = (const float*)d_in[17];
  const float* bfc  = (const float*)d_in[18];
  const int* lengths = (const int*)d_in[19];
  float* out = (float*)d_out;

  const size_t BSH = (size_t)Bz * Sz * Hz;   // 7,864,320
  float* z  = (float*)d_ws;
  float* ao = z + BSH;
  float* bo = ao + BSH;
  u16* qb = (u16*)(bo + BSH);
  u16* kb = qb + BSH;
  u16* vb = kb + BSH;
  u16* wb = (u16*)(vb + BSH);                // 1024x1024 bf16 W^T slot

  dim3 cgrid(32, 32);                        // wconv tiles
  dim3 ggrid(Hz / 128, (Bz * Sz) / 128);     // (8, 60)

  embed_kernel<<<Bz * Sz, 256, 0, stream>>>(x, w_emb, p_emb, lengths, z);
  for (int i = 0; i < Lz; ++i) {
    size_t wo = (size_t)i * Hz * Hz, bo_off = (size_t)i * Hz;
    wconv_kernel<<<cgrid, 256, 0, stream>>>(Wq + wo, wb);
    gemm_mfma<true, false><<<ggrid, 256, 0, stream>>>(z, wb, bq + bo_off, qb);
    wconv_kernel<<<cgrid, 256, 0, stream>>>(Wk + wo, wb);
    gemm_mfma<true, false><<<ggrid, 256, 0, stream>>>(z, wb, bk + bo_off, kb);
    wconv_kernel<<<cgrid, 256, 0, stream>>>(Wv + wo, wb);
    gemm_mfma<true, false><<<ggrid, 256, 0, stream>>>(z, wb, bv + bo_off, vb);
    attention_kernel<<<Bz * NHEADS, 512, 0, stream>>>(qb, kb, vb, lengths, ao);
    add_ln_kernel<<<Bz * Sz, 256, 0, stream>>>(z, ao, ln1s + bo_off, ln1b + bo_off);
    wconv_kernel<<<cgrid, 256, 0, stream>>>(W1 + wo, wb);
    gemm_mfma<false, true><<<ggrid, 256, 0, stream>>>(z, wb, b1 + bo_off, ao);
    wconv_kernel<<<cgrid, 256, 0, stream>>>(W2 + wo, wb);
    gemm_mfma<false, false><<<ggrid, 256, 0, stream>>>(ao, wb, b2 + bo_off, bo);
    add_ln_kernel<<<Bz * Sz, 256, 0, stream>>>(z, bo, ln2s + bo_off, ln2b + bo_off);
  }
  pool_kernel<<<Bz, 256, 0, stream>>>(z, Wfc, bfc, out);
}

// Round 7
// 2769.330 us; speedup vs baseline: 7.0776x; 1.6591x over previous
//
#include <hip/hip_runtime.h>
#include <hip/hip_bf16.h>

#define Bz 32
#define Sz 240
#define Hz 1024
#define Lz 8
#define NHEADS 16
#define NVOCAB 48
#define DHEAD 64
#define VT_STRIDE 264   // u16; 528B rows: 16B-aligned, 2-way-free banks

typedef unsigned short u16;
typedef unsigned int u32;
typedef __attribute__((ext_vector_type(8))) short short8v;
typedef __attribute__((ext_vector_type(4))) float floatx4;

__device__ __forceinline__ int get_len(const int* __restrict__ L, int b) {
  return (L[1] == 0) ? L[2 * b] : L[b];   // int64 vs int32 robustness
}
__device__ __forceinline__ u16 f2bf(float f) {  // RNE fp32->bf16
  u32 u = __float_as_uint(f);
  return (u16)((u + 0x7FFFu + ((u >> 16) & 1u)) >> 16);
}
__device__ __forceinline__ float bf2f(u16 s) {
  return __uint_as_float(((u32)s) << 16);
}

// ---------------- embedding: argmax + gather + posenc (fp32 z) ----------------
__global__ __launch_bounds__(256) void embed_kernel(
    const float* __restrict__ x, const float* __restrict__ w_emb,
    const float* __restrict__ p_emb, const int* __restrict__ lengths,
    float* __restrict__ z) {
  int bs = blockIdx.x;
  int b = bs / Sz, s = bs % Sz;
  __shared__ int stok;
  if (threadIdx.x == 0) {
    const float* xr = x + (size_t)bs * NVOCAB;
    float best = xr[0]; int bi = 0;
    for (int j = 1; j < NVOCAB; ++j) {
      float v = xr[j];
      if (v > best) { best = v; bi = j; }
    }
    stok = bi;
  }
  __syncthreads();
  int tok = stok;
  float valid = (s < get_len(lengths, b)) ? 1.f : 0.f;
  const float* we = w_emb + (size_t)tok * Hz;
  const float* pe = p_emb + (size_t)s * Hz;
  float* zr = z + (size_t)bs * Hz;
  for (int h = threadIdx.x; h < Hz; h += blockDim.x)
    zr[h] = we[h] * valid + pe[h];
}

// ---------------- weight convert+transpose: fp32 W[K][N] -> bf16 Wt[N][K] ----------------
__global__ __launch_bounds__(256) void wconv_kernel(
    const float* __restrict__ W, u16* __restrict__ wt) {
  __shared__ u16 T[32][33];
  int bi = blockIdx.y, bj = blockIdx.x;       // k-tile, n-tile
  int r = threadIdx.x >> 3, c4 = (threadIdx.x & 7) * 4;
  float4 w4 = *(const float4*)(W + (size_t)(bi * 32 + r) * Hz + bj * 32 + c4);
  T[r][c4 + 0] = f2bf(w4.x); T[r][c4 + 1] = f2bf(w4.y);
  T[r][c4 + 2] = f2bf(w4.z); T[r][c4 + 3] = f2bf(w4.w);
  __syncthreads();
  u32 lo = (u32)T[c4 + 0][r] | ((u32)T[c4 + 1][r] << 16);
  u32 hi = (u32)T[c4 + 2][r] | ((u32)T[c4 + 3][r] << 16);
  uint2 val; val.x = lo; val.y = hi;
  *(uint2*)(wt + (size_t)(bj * 32 + r) * Hz + bi * 32 + c4) = val;
}

// ---------------- MFMA GEMM: C[7680,1024] = A(fp32) @ Wt^T(bf16) + bias ----------------
template <bool OUTBF16, bool GELU>
__global__ __launch_bounds__(256) void gemm_mfma(
    const float* __restrict__ A, const u16* __restrict__ Wt,
    const float* __restrict__ bias, void* __restrict__ Cv) {
  __shared__ u16 As[4096];
  __shared__ u16 Bs[4096];
  int tid = threadIdx.x;
  int row0 = blockIdx.y * 128, col0 = blockIdx.x * 128;
  int w = tid >> 6, lane = tid & 63;
  int wr = w >> 1, wc = w & 1;
  floatx4 acc[4][4] = {};

  int r = tid >> 1, kh = tid & 1;
  const float* aptr = A + (size_t)(row0 + r) * Hz + kh * 16;
  const u16* bptr = Wt + (size_t)(col0 + r) * Hz + kh * 16;
  int wbase = (r >> 4) * 512 + kh * 256 + (r & 15) * 8;
  int afrag_off[4], bfrag_off[4];
#pragma unroll
  for (int i = 0; i < 4; ++i) {
    afrag_off[i] = (wr * 4 + i) * 512 + (lane >> 4) * 128 + (lane & 15) * 8;
    bfrag_off[i] = (wc * 4 + i) * 512 + (lane >> 4) * 128 + (lane & 15) * 8;
  }

  for (int k0 = 0; k0 < Hz; k0 += 32) {
    float4 a0 = *(const float4*)(aptr + k0);
    float4 a1 = *(const float4*)(aptr + k0 + 4);
    float4 a2 = *(const float4*)(aptr + k0 + 8);
    float4 a3 = *(const float4*)(aptr + k0 + 12);
    uint4 b01 = *(const uint4*)(bptr + k0);
    uint4 b23 = *(const uint4*)(bptr + k0 + 8);
    uint4 apk0, apk1;
    apk0.x = (u32)f2bf(a0.x) | ((u32)f2bf(a0.y) << 16);
    apk0.y = (u32)f2bf(a0.z) | ((u32)f2bf(a0.w) << 16);
    apk0.z = (u32)f2bf(a1.x) | ((u32)f2bf(a1.y) << 16);
    apk0.w = (u32)f2bf(a1.z) | ((u32)f2bf(a1.w) << 16);
    apk1.x = (u32)f2bf(a2.x) | ((u32)f2bf(a2.y) << 16);
    apk1.y = (u32)f2bf(a2.z) | ((u32)f2bf(a2.w) << 16);
    apk1.z = (u32)f2bf(a3.x) | ((u32)f2bf(a3.y) << 16);
    apk1.w = (u32)f2bf(a3.z) | ((u32)f2bf(a3.w) << 16);
    *(uint4*)(As + wbase) = apk0;
    *(uint4*)(As + wbase + 128) = apk1;
    *(uint4*)(Bs + wbase) = b01;
    *(uint4*)(Bs + wbase + 128) = b23;
    __syncthreads();
    short8v af[4], bf[4];
#pragma unroll
    for (int i = 0; i < 4; ++i) af[i] = *(const short8v*)(As + afrag_off[i]);
#pragma unroll
    for (int i = 0; i < 4; ++i) bf[i] = *(const short8v*)(Bs + bfrag_off[i]);
#pragma unroll
    for (int mi = 0; mi < 4; ++mi)
#pragma unroll
      for (int ni = 0; ni < 4; ++ni)
        acc[mi][ni] = __builtin_amdgcn_mfma_f32_16x16x32_bf16(
            af[mi], bf[ni], acc[mi][ni], 0, 0, 0);
    __syncthreads();
  }

  int rowbase = row0 + wr * 64, colbase = col0 + wc * 64;
#pragma unroll
  for (int ni = 0; ni < 4; ++ni) {
    int col = colbase + ni * 16 + (lane & 15);
    float bcol = bias[col];
#pragma unroll
    for (int mi = 0; mi < 4; ++mi) {
      int rtop = rowbase + mi * 16 + (lane >> 4) * 4;
#pragma unroll
      for (int reg = 0; reg < 4; ++reg) {
        float vv = acc[mi][ni][reg] + bcol;
        if (GELU) vv = 0.5f * vv * (1.f + erff(vv * 0.70710678118654752f));
        if (OUTBF16)
          ((u16*)Cv)[(size_t)(rtop + reg) * Hz + col] = f2bf(vv);
        else
          ((float*)Cv)[(size_t)(rtop + reg) * Hz + col] = vv;
      }
    }
  }
}

// ---------------- MFMA flash attention ----------------
// Block = (b, head, S-half); 256 thr = 4 waves; wave owns 16-row q-tiles.
// Q A-frags + K B-frags: direct 16B global loads (row-contiguous per lane).
// V^T staged once in LDS (keys padded to 256 with ZEROS — the PV tail MFMA
// reads keys 240..255; uninitialized LDS there was round 6's NaN). P routed
// C->A layout via per-wave LDS tile.
__global__ __launch_bounds__(256) void attention_kernel(
    const u16* __restrict__ q, const u16* __restrict__ k,
    const u16* __restrict__ v, const int* __restrict__ lengths,
    float* __restrict__ out) {
  __shared__ u16 Vt[64 * VT_STRIDE];   // [dim][key]
  __shared__ u16 Pb[4][16 * 40];       // per-wave P tile, row stride 40 (80B, 16B-aligned)
  int hh = blockIdx.x & 1;
  int h = (blockIdx.x >> 1) & 15;
  int b = blockIdx.x >> 5;
  int tid = threadIdx.x;
  const size_t base = ((size_t)b * Sz) * Hz + (size_t)h * DHEAD;

  // stage V transposed over padded key range [0,256): zero beyond Sz
  for (int idx = tid; idx < 256 * 16; idx += 256) {
    int key = idx >> 4, d4 = (idx & 15) * 4;
    uint2 vv;
    if (key < Sz) {
      vv = *(const uint2*)(v + base + (size_t)key * Hz + d4);
    } else {
      vv.x = 0u; vv.y = 0u;
    }
    Vt[(d4 + 0) * VT_STRIDE + key] = (u16)(vv.x & 0xFFFF);
    Vt[(d4 + 1) * VT_STRIDE + key] = (u16)(vv.x >> 16);
    Vt[(d4 + 2) * VT_STRIDE + key] = (u16)(vv.y & 0xFFFF);
    Vt[(d4 + 3) * VT_STRIDE + key] = (u16)(vv.y >> 16);
  }
  __syncthreads();

  int w = tid >> 6, lane = tid & 63;
  int qgroup = lane >> 4, qcol = lane & 15;
  int len_b = get_len(lengths, b);

  for (int qt = hh * 8 + w; qt < hh * 8 + 8 && qt < 15; qt += 4) {
    const u16* qrow = q + base + (size_t)(qt * 16 + qcol) * Hz;
    short8v aq0 = *(const short8v*)(qrow + qgroup * 8);
    short8v aq1 = *(const short8v*)(qrow + 32 + qgroup * 8);
    floatx4 o0 = {0.f, 0.f, 0.f, 0.f}, o1 = o0, o2 = o0, o3 = o0;
    float m_run[4] = {-1e30f, -1e30f, -1e30f, -1e30f};
    float l_run[4] = {0.f, 0.f, 0.f, 0.f};
    int nsteps = (qt + 2) >> 1;   // ceil((qt+1)/2) 32-key steps

    for (int st = 0; st < nsteps; ++st) {
      int t0 = 2 * st, t1 = 2 * st + 1;
      bool has1 = (t1 <= qt);
      floatx4 s0 = {0.f, 0.f, 0.f, 0.f};
      {
        const u16* kr = k + base + (size_t)(t0 * 16 + qcol) * Hz;
        short8v bk0 = *(const short8v*)(kr + qgroup * 8);
        short8v bk1 = *(const short8v*)(kr + 32 + qgroup * 8);
        s0 = __builtin_amdgcn_mfma_f32_16x16x32_bf16(aq0, bk0, s0, 0, 0, 0);
        s0 = __builtin_amdgcn_mfma_f32_16x16x32_bf16(aq1, bk1, s0, 0, 0, 0);
      }
      floatx4 s1 = {0.f, 0.f, 0.f, 0.f};
      if (has1) {
        const u16* kr = k + base + (size_t)(t1 * 16 + qcol) * Hz;
        short8v bk0 = *(const short8v*)(kr + qgroup * 8);
        short8v bk1 = *(const short8v*)(kr + 32 + qgroup * 8);
        s1 = __builtin_amdgcn_mfma_f32_16x16x32_bf16(aq0, bk0, s1, 0, 0, 0);
        s1 = __builtin_amdgcn_mfma_f32_16x16x32_bf16(aq1, bk1, s1, 0, 0, 0);
      }
      int kg0 = t0 * 16 + qcol, kg1 = t1 * 16 + qcol;
      float p0[4], p1[4];
#pragma unroll
      for (int rg = 0; rg < 4; ++rg) {
        int row_g = qt * 16 + qgroup * 4 + rg;
        float x0 = (kg0 <= row_g) ? s0[rg] * 0.03125f : -1e30f;
        float x1 = (has1 && kg1 <= row_g) ? s1[rg] * 0.03125f : -1e30f;
        float mx = fmaxf(x0, x1);
        mx = fmaxf(mx, __shfl_xor(mx, 1));
        mx = fmaxf(mx, __shfl_xor(mx, 2));
        mx = fmaxf(mx, __shfl_xor(mx, 4));
        mx = fmaxf(mx, __shfl_xor(mx, 8));
        float mnew = fmaxf(m_run[rg], mx);
        float alpha = __expf(m_run[rg] - mnew);
        float e0 = __expf(x0 - mnew);
        float e1 = __expf(x1 - mnew);
        float rs = e0 + e1;
        rs += __shfl_xor(rs, 1);
        rs += __shfl_xor(rs, 2);
        rs += __shfl_xor(rs, 4);
        rs += __shfl_xor(rs, 8);
        l_run[rg] = l_run[rg] * alpha + rs;
        m_run[rg] = mnew;
        o0[rg] *= alpha; o1[rg] *= alpha; o2[rg] *= alpha; o3[rg] *= alpha;
        p0[rg] = e0; p1[rg] = e1;
      }
      // P: C-layout -> A-layout through per-wave LDS tile
#pragma unroll
      for (int rg = 0; rg < 4; ++rg) {
        int rl = qgroup * 4 + rg;
        Pb[w][rl * 40 + qcol] = f2bf(p0[rg]);
        Pb[w][rl * 40 + 16 + qcol] = f2bf(p1[rg]);
      }
      __asm__ volatile("s_waitcnt lgkmcnt(0)" ::: "memory");
      short8v pa = *(const short8v*)(&Pb[w][qcol * 40 + qgroup * 8]);
      int kb0 = st * 32 + qgroup * 8;
      short8v bv0 = *(const short8v*)(&Vt[(0 * 16 + qcol) * VT_STRIDE + kb0]);
      short8v bv1 = *(const short8v*)(&Vt[(1 * 16 + qcol) * VT_STRIDE + kb0]);
      short8v bv2 = *(const short8v*)(&Vt[(2 * 16 + qcol) * VT_STRIDE + kb0]);
      short8v bv3 = *(const short8v*)(&Vt[(3 * 16 + qcol) * VT_STRIDE + kb0]);
      o0 = __builtin_amdgcn_mfma_f32_16x16x32_bf16(pa, bv0, o0, 0, 0, 0);
      o1 = __builtin_amdgcn_mfma_f32_16x16x32_bf16(pa, bv1, o1, 0, 0, 0);
      o2 = __builtin_amdgcn_mfma_f32_16x16x32_bf16(pa, bv2, o2, 0, 0, 0);
      o3 = __builtin_amdgcn_mfma_f32_16x16x32_bf16(pa, bv3, o3, 0, 0, 0);
    }

#pragma unroll
    for (int rg = 0; rg < 4; ++rg) {
      int row_g = qt * 16 + qgroup * 4 + rg;
      float vmask = (row_g < len_b) ? (1.f / l_run[rg]) : 0.f;
      float* op = out + ((size_t)b * Sz + row_g) * Hz + (size_t)h * DHEAD + qcol;
      op[0]  = o0[rg] * vmask;
      op[16] = o1[rg] * vmask;
      op[32] = o2[rg] * vmask;
      op[48] = o3[rg] * vmask;
    }
  }
}

// ---------------- residual + LayerNorm, in place on z ----------------
__global__ __launch_bounds__(256) void add_ln_kernel(
    float* __restrict__ z, const float* __restrict__ r,
    const float* __restrict__ gamma, const float* __restrict__ beta) {
  int bs = blockIdx.x, tid = threadIdx.x;
  size_t base = (size_t)bs * Hz;
  __shared__ float sred[256];
  float vals[4];
  float sum = 0.f;
#pragma unroll
  for (int j = 0; j < 4; ++j) {
    int hh = tid + j * 256;
    vals[j] = z[base + hh] + r[base + hh];
    sum += vals[j];
  }
  sred[tid] = sum; __syncthreads();
  for (int off = 128; off > 0; off >>= 1) {
    if (tid < off) sred[tid] += sred[tid + off];
    __syncthreads();
  }
  float mean = sred[0] * (1.f / Hz); __syncthreads();
  float sq = 0.f;
#pragma unroll
  for (int j = 0; j < 4; ++j) { float d = vals[j] - mean; sq += d * d; }
  sred[tid] = sq; __syncthreads();
  for (int off = 128; off > 0; off >>= 1) {
    if (tid < off) sred[tid] += sred[tid + off];
    __syncthreads();
  }
  float rstd = rsqrtf(sred[0] * (1.f / Hz) + 1e-5f);
#pragma unroll
  for (int j = 0; j < 4; ++j) {
    int hh = tid + j * 256;
    z[base + hh] = (vals[j] - mean) * rstd * gamma[hh] + beta[hh];
  }
}

// ---------------- mean-pool + FC + softmax -> fp32 out ----------------
__global__ __launch_bounds__(256) void pool_kernel(
    const float* __restrict__ z, const float* __restrict__ Wfc,
    const float* __restrict__ bfc, float* __restrict__ out) {
  int b = blockIdx.x, tid = threadIdx.x;
  __shared__ float red[256][4];
  float acc[4] = {0.f, 0.f, 0.f, 0.f};
  for (int hh = tid; hh < Hz; hh += 256) {
    float s = 0.f;
    for (int sp = 0; sp < Sz; ++sp) s += z[((size_t)(b * Sz + sp)) * Hz + hh];
    float z2 = s * (1.f / Sz);
#pragma unroll
    for (int c = 0; c < 4; ++c) acc[c] += z2 * Wfc[hh * 4 + c];
  }
#pragma unroll
  for (int c = 0; c < 4; ++c) red[tid][c] = acc[c];
  __syncthreads();
  for (int off = 128; off > 0; off >>= 1) {
    if (tid < off)
#pragma unroll
      for (int c = 0; c < 4; ++c) red[tid][c] += red[tid + off][c];
    __syncthreads();
  }
  if (tid == 0) {
    float lg[4], m = -1e30f;
#pragma unroll
    for (int c = 0; c < 4; ++c) { lg[c] = red[0][c] + bfc[c]; m = fmaxf(m, lg[c]); }
    float s = 0.f;
#pragma unroll
    for (int c = 0; c < 4; ++c) { lg[c] = expf(lg[c] - m); s += lg[c]; }
    float inv = 1.f / s;
#pragma unroll
    for (int c = 0; c < 4; ++c) out[b * 4 + c] = lg[c] * inv;
  }
}

extern "C" void kernel_launch(void* const* d_in, const int* in_sizes, int n_in,
                              void* d_out, int out_size, void* d_ws, size_t ws_size,
                              hipStream_t stream) {
  const float* x     = (const float*)d_in[0];
  const float* w_emb = (const float*)d_in[1];
  const float* p_emb = (const float*)d_in[2];
  const float* Wq = (const float*)d_in[3];
  const float* bq = (const float*)d_in[4];
  const float* Wk = (const float*)d_in[5];
  const float* bk = (const float*)d_in[6];
  const float* Wv = (const float*)d_in[7];
  const float* bv = (const float*)d_in[8];
  const float* W1 = (const float*)d_in[9];
  const float* b1 = (const float*)d_in[10];
  const float* W2 = (const float*)d_in[11];
  const float* b2 = (const float*)d_in[12];
  const float* ln1s = (const float*)d_in[13];
  const float* ln1b = (const float*)d_in[14];
  const float* ln2s = (const float*)d_in[15];
  const float* ln2b = (const float*)d_in[16];
  const float* Wfc  = (const float*)d_in[17];
  const float* bfc  = (const float*)d_in[18];
  const int* lengths = (const int*)d_in[19];
  float* out = (float*)d_out;

  const size_t BSH = (size_t)Bz * Sz * Hz;   // 7,864,320
  float* z  = (float*)d_ws;
  float* ao = z + BSH;
  float* bo = ao + BSH;
  u16* qb = (u16*)(bo + BSH);
  u16* kb = qb + BSH;
  u16* vb = kb + BSH;
  u16* wb = (u16*)(vb + BSH);                // 1024x1024 bf16 W^T slot

  dim3 cgrid(32, 32);
  dim3 ggrid(Hz / 128, (Bz * Sz) / 128);     // (8, 60)

  embed_kernel<<<Bz * Sz, 256, 0, stream>>>(x, w_emb, p_emb, lengths, z);
  for (int i = 0; i < Lz; ++i) {
    size_t wo = (size_t)i * Hz * Hz, bo_off = (size_t)i * Hz;
    wconv_kernel<<<cgrid, 256, 0, stream>>>(Wq + wo, wb);
    gemm_mfma<true, false><<<ggrid, 256, 0, stream>>>(z, wb, bq + bo_off, qb);
    wconv_kernel<<<cgrid, 256, 0, stream>>>(Wk + wo, wb);
    gemm_mfma<true, false><<<ggrid, 256, 0, stream>>>(z, wb, bk + bo_off, kb);
    wconv_kernel<<<cgrid, 256, 0, stream>>>(Wv + wo, wb);
    gemm_mfma<true, false><<<ggrid, 256, 0, stream>>>(z, wb, bv + bo_off, vb);
    attention_kernel<<<Bz * NHEADS * 2, 256, 0, stream>>>(qb, kb, vb, lengths, ao);
    add_ln_kernel<<<Bz * Sz, 256, 0, stream>>>(z, ao, ln1s + bo_off, ln1b + bo_off);
    wconv_kernel<<<cgrid, 256, 0, stream>>>(W1 + wo, wb);
    gemm_mfma<false, true><<<ggrid, 256, 0, stream>>>(z, wb, b1 + bo_off, ao);
    wconv_kernel<<<cgrid, 256, 0, stream>>>(W2 + wo, wb);
    gemm_mfma<false, false><<<ggrid, 256, 0, stream>>>(ao, wb, b2 + bo_off, bo);
    add_ln_kernel<<<Bz * Sz, 256, 0, stream>>>(z, bo, ln2s + bo_off, ln2b + bo_off);
  }
  pool_kernel<<<Bz, 256, 0, stream>>>(z, Wfc, bfc, out);
}

// Round 8
// 2273.244 us; speedup vs baseline: 8.6221x; 1.2182x over previous
//
#include <hip/hip_runtime.h>
#include <hip/hip_bf16.h>

#define Bz 32
#define Sz 240
#define Hz 1024
#define Lz 8
#define NHEADS 16
#define NVOCAB 48
#define DHEAD 64
#define VT_STRIDE 264

typedef unsigned short u16;
typedef unsigned int u32;
typedef __attribute__((ext_vector_type(8))) short short8v;
typedef __attribute__((ext_vector_type(4))) float floatx4;

__device__ __forceinline__ int get_len(const int* __restrict__ L, int b) {
  return (L[1] == 0) ? L[2 * b] : L[b];
}
__device__ __forceinline__ u16 f2bf(float f) {  // RNE fp32->bf16
  u32 u = __float_as_uint(f);
  return (u16)((u + 0x7FFFu + ((u >> 16) & 1u)) >> 16);
}
__device__ __forceinline__ float bf2f(u16 s) {
  return __uint_as_float(((u32)s) << 16);
}
// async global->LDS, 16B per lane; LDS dest = wave-uniform base + lane*16
__device__ __forceinline__ void async_copy16(const u16* g, u16* l) {
  __builtin_amdgcn_global_load_lds(
      (const __attribute__((address_space(1))) u32*)g,
      (__attribute__((address_space(3))) u32*)l, 16, 0, 0);
}

// ---------------- embedding ----------------
__global__ __launch_bounds__(256) void embed_kernel(
    const float* __restrict__ x, const float* __restrict__ w_emb,
    const float* __restrict__ p_emb, const int* __restrict__ lengths,
    float* __restrict__ z, u16* __restrict__ z_bf) {
  int bs = blockIdx.x;
  int b = bs / Sz, s = bs % Sz;
  __shared__ int stok;
  if (threadIdx.x == 0) {
    const float* xr = x + (size_t)bs * NVOCAB;
    float best = xr[0]; int bi = 0;
    for (int j = 1; j < NVOCAB; ++j) {
      float v = xr[j];
      if (v > best) { best = v; bi = j; }
    }
    stok = bi;
  }
  __syncthreads();
  int tok = stok;
  float valid = (s < get_len(lengths, b)) ? 1.f : 0.f;
  const float* we = w_emb + (size_t)tok * Hz;
  const float* pe = p_emb + (size_t)s * Hz;
  size_t base = (size_t)bs * Hz;
  for (int h = threadIdx.x; h < Hz; h += blockDim.x) {
    float v = we[h] * valid + pe[h];
    z[base + h] = v;
    z_bf[base + h] = f2bf(v);
  }
}

// ---------------- bias concat: [L][3072] = bq|bk|bv ----------------
__global__ __launch_bounds__(256) void bias_concat(
    const float* __restrict__ bq, const float* __restrict__ bk,
    const float* __restrict__ bv, float* __restrict__ dst) {
  int i = blockIdx.x * 256 + threadIdx.x;     // Lz*3072
  int l = i / 3072, c = i % 3072;
  float v = (c < 1024) ? bq[l * 1024 + c]
          : (c < 2048) ? bk[l * 1024 + c - 1024]
                       : bv[l * 1024 + c - 2048];
  dst[i] = v;
}

// ---------------- weight convert+transpose, 5 matrices per layer ----------------
struct WconvArgs { const float* src[5]; u16* dst[5]; };
__global__ __launch_bounds__(256) void wconv5(WconvArgs a) {
  __shared__ u16 T[32][33];
  const float* W = a.src[blockIdx.z];
  u16* wt = a.dst[blockIdx.z];
  int bi = blockIdx.y, bj = blockIdx.x;
  int r = threadIdx.x >> 3, c4 = (threadIdx.x & 7) * 4;
  float4 w4 = *(const float4*)(W + (size_t)(bi * 32 + r) * Hz + bj * 32 + c4);
  T[r][c4 + 0] = f2bf(w4.x); T[r][c4 + 1] = f2bf(w4.y);
  T[r][c4 + 2] = f2bf(w4.z); T[r][c4 + 3] = f2bf(w4.w);
  __syncthreads();
  u32 lo = (u32)T[c4 + 0][r] | ((u32)T[c4 + 1][r] << 16);
  u32 hi = (u32)T[c4 + 2][r] | ((u32)T[c4 + 3][r] << 16);
  uint2 val; val.x = lo; val.y = hi;
  *(uint2*)(wt + (size_t)(bj * 32 + r) * Hz + bi * 32 + c4) = val;
}

// ---------------- MFMA GEMM: C[7680,nco] = A(bf16)[7680,1024] @ Wt[nco,1024]^T + bias ----
// 128x128 tile, BK=32, global_load_lds(16B) staging in fragment order.
// 1D grid with 8-row superblock swizzle: XCD k (id%8) keeps rows==k(mod 8) in its L2.
template <bool OUTBF16, bool GELU>
__global__ __launch_bounds__(256) void gemm_mfma(
    const u16* __restrict__ A, const u16* __restrict__ Wt,
    const float* __restrict__ bias, void* __restrict__ Cv, int nco) {
  __shared__ u16 As[4096];
  __shared__ u16 Bs[4096];
  int tid = threadIdx.x;
  int xt = nco >> 7;
  int id = blockIdx.x;
  int per = xt << 3;
  int g = id / per;
  int rr = id - g * per;
  int ys = 60 - (g << 3); ys = ys > 8 ? 8 : ys;
  int row0 = ((g << 3) + rr % ys) * 128;
  int col0 = (rr / ys) * 128;

  int w = tid >> 6, lane = tid & 63;
  int l15 = lane & 15, lq = lane >> 4;
  int wr = w >> 1, wc = w & 1;
  floatx4 acc[4][4] = {};

  const u16* gA0 = A + (size_t)(row0 + 32 * w + l15) * 1024 + 8 * lq;
  const u16* gA1 = gA0 + 16 * 1024;
  const u16* gB0 = Wt + (size_t)(col0 + 32 * w + l15) * 1024 + 8 * lq;
  const u16* gB1 = gB0 + 16 * 1024;
  u16* lA0 = As + (2 * w) * 512;
  u16* lA1 = lA0 + 512;
  u16* lB0 = Bs + (2 * w) * 512;
  u16* lB1 = lB0 + 512;

  int afrag_off[4], bfrag_off[4];
#pragma unroll
  for (int i = 0; i < 4; ++i) {
    afrag_off[i] = (wr * 4 + i) * 512 + lq * 128 + l15 * 8;
    bfrag_off[i] = (wc * 4 + i) * 512 + lq * 128 + l15 * 8;
  }

  for (int k0 = 0; k0 < 1024; k0 += 32) {
    async_copy16(gA0 + k0, lA0);
    async_copy16(gA1 + k0, lA1);
    async_copy16(gB0 + k0, lB0);
    async_copy16(gB1 + k0, lB1);
    __syncthreads();
    short8v af[4], bf[4];
#pragma unroll
    for (int i = 0; i < 4; ++i) af[i] = *(const short8v*)(As + afrag_off[i]);
#pragma unroll
    for (int i = 0; i < 4; ++i) bf[i] = *(const short8v*)(Bs + bfrag_off[i]);
#pragma unroll
    for (int mi = 0; mi < 4; ++mi)
#pragma unroll
      for (int ni = 0; ni < 4; ++ni)
        acc[mi][ni] = __builtin_amdgcn_mfma_f32_16x16x32_bf16(
            af[mi], bf[ni], acc[mi][ni], 0, 0, 0);
    __syncthreads();
  }

  int rowbase = row0 + wr * 64, colbase = col0 + wc * 64;
#pragma unroll
  for (int ni = 0; ni < 4; ++ni) {
    int col = colbase + ni * 16 + l15;
    float bcol = bias[col];
#pragma unroll
    for (int mi = 0; mi < 4; ++mi) {
      int rtop = rowbase + mi * 16 + lq * 4;
#pragma unroll
      for (int reg = 0; reg < 4; ++reg) {
        float vv = acc[mi][ni][reg] + bcol;
        if (GELU) vv = 0.5f * vv * (1.f + erff(vv * 0.70710678118654752f));
        if (OUTBF16)
          ((u16*)Cv)[(size_t)(rtop + reg) * nco + col] = f2bf(vv);
        else
          ((float*)Cv)[(size_t)(rtop + reg) * nco + col] = vv;
      }
    }
  }
}

// ---------------- MFMA flash attention (packed qkv input, stride 3072) -----------
__global__ __launch_bounds__(256) void attention_kernel(
    const u16* __restrict__ qkv, const int* __restrict__ lengths,
    float* __restrict__ out) {
  const int LDQ = 3072;
  __shared__ u16 Vt[64 * VT_STRIDE];
  __shared__ u16 Pb[4][16 * 40];
  int hh = blockIdx.x & 1;
  int h = (blockIdx.x >> 1) & 15;
  int b = blockIdx.x >> 5;
  int tid = threadIdx.x;
  const size_t base = ((size_t)b * Sz) * LDQ + (size_t)h * DHEAD;
  const u16* qp = qkv + base;
  const u16* kp = qkv + base + 1024;
  const u16* vp = qkv + base + 2048;

  for (int idx = tid; idx < 256 * 16; idx += 256) {
    int key = idx >> 4, d4 = (idx & 15) * 4;
    uint2 vv;
    if (key < Sz) vv = *(const uint2*)(vp + (size_t)key * LDQ + d4);
    else { vv.x = 0u; vv.y = 0u; }
    Vt[(d4 + 0) * VT_STRIDE + key] = (u16)(vv.x & 0xFFFF);
    Vt[(d4 + 1) * VT_STRIDE + key] = (u16)(vv.x >> 16);
    Vt[(d4 + 2) * VT_STRIDE + key] = (u16)(vv.y & 0xFFFF);
    Vt[(d4 + 3) * VT_STRIDE + key] = (u16)(vv.y >> 16);
  }
  __syncthreads();

  int w = tid >> 6, lane = tid & 63;
  int qgroup = lane >> 4, qcol = lane & 15;
  int len_b = get_len(lengths, b);

  for (int qt = hh * 8 + w; qt < hh * 8 + 8 && qt < 15; qt += 4) {
    const u16* qrow = qp + (size_t)(qt * 16 + qcol) * LDQ;
    short8v aq0 = *(const short8v*)(qrow + qgroup * 8);
    short8v aq1 = *(const short8v*)(qrow + 32 + qgroup * 8);
    floatx4 o0 = {0.f, 0.f, 0.f, 0.f}, o1 = o0, o2 = o0, o3 = o0;
    float m_run[4] = {-1e30f, -1e30f, -1e30f, -1e30f};
    float l_run[4] = {0.f, 0.f, 0.f, 0.f};
    int nsteps = (qt + 2) >> 1;

    for (int st = 0; st < nsteps; ++st) {
      int t0 = 2 * st, t1 = 2 * st + 1;
      bool has1 = (t1 <= qt);
      floatx4 s0 = {0.f, 0.f, 0.f, 0.f};
      {
        const u16* kr = kp + (size_t)(t0 * 16 + qcol) * LDQ;
        short8v bk0 = *(const short8v*)(kr + qgroup * 8);
        short8v bk1 = *(const short8v*)(kr + 32 + qgroup * 8);
        s0 = __builtin_amdgcn_mfma_f32_16x16x32_bf16(aq0, bk0, s0, 0, 0, 0);
        s0 = __builtin_amdgcn_mfma_f32_16x16x32_bf16(aq1, bk1, s0, 0, 0, 0);
      }
      floatx4 s1 = {0.f, 0.f, 0.f, 0.f};
      if (has1) {
        const u16* kr = kp + (size_t)(t1 * 16 + qcol) * LDQ;
        short8v bk0 = *(const short8v*)(kr + qgroup * 8);
        short8v bk1 = *(const short8v*)(kr + 32 + qgroup * 8);
        s1 = __builtin_amdgcn_mfma_f32_16x16x32_bf16(aq0, bk0, s1, 0, 0, 0);
        s1 = __builtin_amdgcn_mfma_f32_16x16x32_bf16(aq1, bk1, s1, 0, 0, 0);
      }
      int kg0 = t0 * 16 + qcol, kg1 = t1 * 16 + qcol;
      float p0[4], p1[4];
#pragma unroll
      for (int rg = 0; rg < 4; ++rg) {
        int row_g = qt * 16 + qgroup * 4 + rg;
        float x0 = (kg0 <= row_g) ? s0[rg] * 0.03125f : -1e30f;
        float x1 = (has1 && kg1 <= row_g) ? s1[rg] * 0.03125f : -1e30f;
        float mx = fmaxf(x0, x1);
        mx = fmaxf(mx, __shfl_xor(mx, 1));
        mx = fmaxf(mx, __shfl_xor(mx, 2));
        mx = fmaxf(mx, __shfl_xor(mx, 4));
        mx = fmaxf(mx, __shfl_xor(mx, 8));
        float mnew = fmaxf(m_run[rg], mx);
        float alpha = __expf(m_run[rg] - mnew);
        float e0 = __expf(x0 - mnew);
        float e1 = __expf(x1 - mnew);
        float rs = e0 + e1;
        rs += __shfl_xor(rs, 1);
        rs += __shfl_xor(rs, 2);
        rs += __shfl_xor(rs, 4);
        rs += __shfl_xor(rs, 8);
        l_run[rg] = l_run[rg] * alpha + rs;
        m_run[rg] = mnew;
        o0[rg] *= alpha; o1[rg] *= alpha; o2[rg] *= alpha; o3[rg] *= alpha;
        p0[rg] = e0; p1[rg] = e1;
      }
#pragma unroll
      for (int rg = 0; rg < 4; ++rg) {
        int rl = qgroup * 4 + rg;
        Pb[w][rl * 40 + qcol] = f2bf(p0[rg]);
        Pb[w][rl * 40 + 16 + qcol] = f2bf(p1[rg]);
      }
      __asm__ volatile("s_waitcnt lgkmcnt(0)" ::: "memory");
      short8v pa = *(const short8v*)(&Pb[w][qcol * 40 + qgroup * 8]);
      int kb0 = st * 32 + qgroup * 8;
      short8v bv0 = *(const short8v*)(&Vt[(0 * 16 + qcol) * VT_STRIDE + kb0]);
      short8v bv1 = *(const short8v*)(&Vt[(1 * 16 + qcol) * VT_STRIDE + kb0]);
      short8v bv2 = *(const short8v*)(&Vt[(2 * 16 + qcol) * VT_STRIDE + kb0]);
      short8v bv3 = *(const short8v*)(&Vt[(3 * 16 + qcol) * VT_STRIDE + kb0]);
      o0 = __builtin_amdgcn_mfma_f32_16x16x32_bf16(pa, bv0, o0, 0, 0, 0);
      o1 = __builtin_amdgcn_mfma_f32_16x16x32_bf16(pa, bv1, o1, 0, 0, 0);
      o2 = __builtin_amdgcn_mfma_f32_16x16x32_bf16(pa, bv2, o2, 0, 0, 0);
      o3 = __builtin_amdgcn_mfma_f32_16x16x32_bf16(pa, bv3, o3, 0, 0, 0);
    }

#pragma unroll
    for (int rg = 0; rg < 4; ++rg) {
      int row_g = qt * 16 + qgroup * 4 + rg;
      float vmask = (row_g < len_b) ? (1.f / l_run[rg]) : 0.f;
      float* op = out + ((size_t)b * Sz + row_g) * Hz + (size_t)h * DHEAD + qcol;
      op[0]  = o0[rg] * vmask;
      op[16] = o1[rg] * vmask;
      op[32] = o2[rg] * vmask;
      op[48] = o3[rg] * vmask;
    }
  }
}

// ---------------- residual + LayerNorm, in place on z; refreshes z_bf ----------------
__global__ __launch_bounds__(256) void add_ln_kernel(
    float* __restrict__ z, u16* __restrict__ z_bf, const float* __restrict__ r,
    const float* __restrict__ gamma, const float* __restrict__ beta) {
  int bs = blockIdx.x, tid = threadIdx.x;
  size_t base = (size_t)bs * Hz;
  __shared__ float sred[256];
  float vals[4];
  float sum = 0.f;
#pragma unroll
  for (int j = 0; j < 4; ++j) {
    int hh = tid + j * 256;
    vals[j] = z[base + hh] + r[base + hh];
    sum += vals[j];
  }
  sred[tid] = sum; __syncthreads();
  for (int off = 128; off > 0; off >>= 1) {
    if (tid < off) sred[tid] += sred[tid + off];
    __syncthreads();
  }
  float mean = sred[0] * (1.f / Hz); __syncthreads();
  float sq = 0.f;
#pragma unroll
  for (int j = 0; j < 4; ++j) { float d = vals[j] - mean; sq += d * d; }
  sred[tid] = sq; __syncthreads();
  for (int off = 128; off > 0; off >>= 1) {
    if (tid < off) sred[tid] += sred[tid + off];
    __syncthreads();
  }
  float rstd = rsqrtf(sred[0] * (1.f / Hz) + 1e-5f);
#pragma unroll
  for (int j = 0; j < 4; ++j) {
    int hh = tid + j * 256;
    float v = (vals[j] - mean) * rstd * gamma[hh] + beta[hh];
    z[base + hh] = v;
    z_bf[base + hh] = f2bf(v);
  }
}

// ---------------- mean-pool + FC + softmax -> fp32 out ----------------
__global__ __launch_bounds__(256) void pool_kernel(
    const float* __restrict__ z, const float* __restrict__ Wfc,
    const float* __restrict__ bfc, float* __restrict__ out) {
  int b = blockIdx.x, tid = threadIdx.x;
  __shared__ float red[256][4];
  float acc[4] = {0.f, 0.f, 0.f, 0.f};
  for (int hh = tid; hh < Hz; hh += 256) {
    float s = 0.f;
    for (int sp = 0; sp < Sz; ++sp) s += z[((size_t)(b * Sz + sp)) * Hz + hh];
    float z2 = s * (1.f / Sz);
#pragma unroll
    for (int c = 0; c < 4; ++c) acc[c] += z2 * Wfc[hh * 4 + c];
  }
#pragma unroll
  for (int c = 0; c < 4; ++c) red[tid][c] = acc[c];
  __syncthreads();
  for (int off = 128; off > 0; off >>= 1) {
    if (tid < off)
#pragma unroll
      for (int c = 0; c < 4; ++c) red[tid][c] += red[tid + off][c];
    __syncthreads();
  }
  if (tid == 0) {
    float lg[4], m = -1e30f;
#pragma unroll
    for (int c = 0; c < 4; ++c) { lg[c] = red[0][c] + bfc[c]; m = fmaxf(m, lg[c]); }
    float s = 0.f;
#pragma unroll
    for (int c = 0; c < 4; ++c) { lg[c] = expf(lg[c] - m); s += lg[c]; }
    float inv = 1.f / s;
#pragma unroll
    for (int c = 0; c < 4; ++c) out[b * 4 + c] = lg[c] * inv;
  }
}

extern "C" void kernel_launch(void* const* d_in, const int* in_sizes, int n_in,
                              void* d_out, int out_size, void* d_ws, size_t ws_size,
                              hipStream_t stream) {
  const float* x     = (const float*)d_in[0];
  const float* w_emb = (const float*)d_in[1];
  const float* p_emb = (const float*)d_in[2];
  const float* Wq = (const float*)d_in[3];
  const float* bq = (const float*)d_in[4];
  const float* Wk = (const float*)d_in[5];
  const float* bk = (const float*)d_in[6];
  const float* Wv = (const float*)d_in[7];
  const float* bv = (const float*)d_in[8];
  const float* W1 = (const float*)d_in[9];
  const float* b1 = (const float*)d_in[10];
  const float* W2 = (const float*)d_in[11];
  const float* b2 = (const float*)d_in[12];
  const float* ln1s = (const float*)d_in[13];
  const float* ln1b = (const float*)d_in[14];
  const float* ln2s = (const float*)d_in[15];
  const float* ln2b = (const float*)d_in[16];
  const float* Wfc  = (const float*)d_in[17];
  const float* bfc  = (const float*)d_in[18];
  const int* lengths = (const int*)d_in[19];
  float* out = (float*)d_out;

  const size_t BSH = (size_t)Bz * Sz * Hz;   // 7,864,320
  float* z    = (float*)d_ws;                // fp32 BSH
  float* ao   = z + BSH;                     // fp32 BSH (attn out / residual)
  u16* z_bf   = (u16*)(ao + BSH);            // bf16 BSH
  u16* ffb    = z_bf + BSH;                  // bf16 BSH (FF1 out)
  u16* qkv    = ffb + BSH;                   // bf16 3*BSH (also aliased as fp32 FF2 out)
  u16* wt     = qkv + 3 * BSH;               // bf16 5M (qkv 3M | ff1 1M | ff2 1M)
  float* bqkv = (float*)(wt + 5 * 1024 * 1024);  // Lz*3072
  float* bo_f = (float*)qkv;                 // FF2 fp32 out aliases qkv (dead by then)

  embed_kernel<<<Bz * Sz, 256, 0, stream>>>(x, w_emb, p_emb, lengths, z, z_bf);
  bias_concat<<<Lz * 3072 / 256, 256, 0, stream>>>(bq, bk, bv, bqkv);

  for (int i = 0; i < Lz; ++i) {
    size_t wo = (size_t)i * Hz * Hz, bo = (size_t)i * Hz;
    WconvArgs wa;
    wa.src[0] = Wq + wo; wa.src[1] = Wk + wo; wa.src[2] = Wv + wo;
    wa.src[3] = W1 + wo; wa.src[4] = W2 + wo;
    wa.dst[0] = wt;                     wa.dst[1] = wt + 1024 * 1024;
    wa.dst[2] = wt + 2 * 1024 * 1024;   wa.dst[3] = wt + 3 * 1024 * 1024;
    wa.dst[4] = wt + 4 * 1024 * 1024;
    wconv5<<<dim3(32, 32, 5), 256, 0, stream>>>(wa);

    gemm_mfma<true, false><<<60 * 24, 256, 0, stream>>>(
        z_bf, wt, bqkv + (size_t)i * 3072, qkv, 3072);
    attention_kernel<<<Bz * NHEADS * 2, 256, 0, stream>>>(qkv, lengths, ao);
    add_ln_kernel<<<Bz * Sz, 256, 0, stream>>>(z, z_bf, ao, ln1s + bo, ln1b + bo);
    gemm_mfma<true, true><<<60 * 8, 256, 0, stream>>>(
        z_bf, wt + 3 * 1024 * 1024, b1 + bo, ffb, 1024);
    gemm_mfma<false, false><<<60 * 8, 256, 0, stream>>>(
        ffb, wt + 4 * 1024 * 1024, b2 + bo, bo_f, 1024);
    add_ln_kernel<<<Bz * Sz, 256, 0, stream>>>(z, z_bf, bo_f, ln2s + bo, ln2b + bo);
  }
  pool_kernel<<<Bz, 256, 0, stream>>>(z, Wfc, bfc, out);
}

// Round 9
// 2239.379 us; speedup vs baseline: 8.7525x; 1.0151x over previous
//
#include <hip/hip_runtime.h>
#include <hip/hip_bf16.h>

#define Bz 32
#define Sz 240
#define Hz 1024
#define Lz 8
#define NHEADS 16
#define NVOCAB 48
#define DHEAD 64
#define VT_STRIDE 264

typedef unsigned short u16;
typedef unsigned int u32;
typedef __attribute__((ext_vector_type(8))) short short8v;
typedef __attribute__((ext_vector_type(4))) float floatx4;

__device__ __forceinline__ int get_len(const int* __restrict__ L, int b) {
  return (L[1] == 0) ? L[2 * b] : L[b];
}
__device__ __forceinline__ u16 f2bf(float f) {  // RNE fp32->bf16
  u32 u = __float_as_uint(f);
  return (u16)((u + 0x7FFFu + ((u >> 16) & 1u)) >> 16);
}
__device__ __forceinline__ float bf2f(u16 s) {
  return __uint_as_float(((u32)s) << 16);
}
__device__ __forceinline__ void async_copy16(const u16* g, u16* l) {
  __builtin_amdgcn_global_load_lds(
      (const __attribute__((address_space(1))) u32*)g,
      (__attribute__((address_space(3))) u32*)l, 16, 0, 0);
}

// ---------------- embedding ----------------
__global__ __launch_bounds__(256) void embed_kernel(
    const float* __restrict__ x, const float* __restrict__ w_emb,
    const float* __restrict__ p_emb, const int* __restrict__ lengths,
    float* __restrict__ z, u16* __restrict__ z_bf) {
  int bs = blockIdx.x;
  int b = bs / Sz, s = bs % Sz;
  __shared__ int stok;
  if (threadIdx.x == 0) {
    const float* xr = x + (size_t)bs * NVOCAB;
    float best = xr[0]; int bi = 0;
    for (int j = 1; j < NVOCAB; ++j) {
      float v = xr[j];
      if (v > best) { best = v; bi = j; }
    }
    stok = bi;
  }
  __syncthreads();
  int tok = stok;
  float valid = (s < get_len(lengths, b)) ? 1.f : 0.f;
  const float* we = w_emb + (size_t)tok * Hz;
  const float* pe = p_emb + (size_t)s * Hz;
  size_t base = (size_t)bs * Hz;
  for (int h = threadIdx.x; h < Hz; h += blockDim.x) {
    float v = we[h] * valid + pe[h];
    z[base + h] = v;
    z_bf[base + h] = f2bf(v);
  }
}

// ---------------- bias concat: [L][3072] = bq|bk|bv ----------------
__global__ __launch_bounds__(256) void bias_concat(
    const float* __restrict__ bq, const float* __restrict__ bk,
    const float* __restrict__ bv, float* __restrict__ dst) {
  int i = blockIdx.x * 256 + threadIdx.x;
  int l = i / 3072, c = i % 3072;
  float v = (c < 1024) ? bq[l * 1024 + c]
          : (c < 2048) ? bk[l * 1024 + c - 1024]
                       : bv[l * 1024 + c - 2048];
  dst[i] = v;
}

// ---------------- weight convert+transpose, 5 matrices per layer ----------------
struct WconvArgs { const float* src[5]; u16* dst[5]; };
__global__ __launch_bounds__(256) void wconv5(WconvArgs a) {
  __shared__ u16 T[32][33];
  const float* W = a.src[blockIdx.z];
  u16* wt = a.dst[blockIdx.z];
  int bi = blockIdx.y, bj = blockIdx.x;
  int r = threadIdx.x >> 3, c4 = (threadIdx.x & 7) * 4;
  float4 w4 = *(const float4*)(W + (size_t)(bi * 32 + r) * Hz + bj * 32 + c4);
  T[r][c4 + 0] = f2bf(w4.x); T[r][c4 + 1] = f2bf(w4.y);
  T[r][c4 + 2] = f2bf(w4.z); T[r][c4 + 3] = f2bf(w4.w);
  __syncthreads();
  u32 lo = (u32)T[c4 + 0][r] | ((u32)T[c4 + 1][r] << 16);
  u32 hi = (u32)T[c4 + 2][r] | ((u32)T[c4 + 3][r] << 16);
  uint2 val; val.x = lo; val.y = hi;
  *(uint2*)(wt + (size_t)(bj * 32 + r) * Hz + bi * 32 + c4) = val;
}

// ---------------- MFMA GEMM, double-buffered LDS ----------------
// C[7680,nco] = A(bf16)[7680,1024] @ Wt[nco,1024]^T + bias (+resid)
// 128x128 tile, BK=32, global_load_lds(16B); prefetch issued AFTER barrier so
// it overlaps the 16 MFMAs; next barrier's vmcnt-drain is then nearly free.
template <bool OUTBF16, bool GELU, bool RESID>
__global__ __launch_bounds__(256) void gemm_mfma(
    const u16* __restrict__ A, const u16* __restrict__ Wt,
    const float* __restrict__ bias, const float* __restrict__ resid,
    void* __restrict__ Cv, int nco) {
  __shared__ u16 As[2][4096];
  __shared__ u16 Bs[2][4096];
  int tid = threadIdx.x;
  int xt = nco >> 7;
  int id = blockIdx.x;
  int per = xt << 3;
  int g = id / per;
  int rr = id - g * per;
  int ys = 60 - (g << 3); ys = ys > 8 ? 8 : ys;
  int row0 = ((g << 3) + rr % ys) * 128;
  int col0 = (rr / ys) * 128;

  int w = tid >> 6, lane = tid & 63;
  int l15 = lane & 15, lq = lane >> 4;
  int wr = w >> 1, wc = w & 1;
  floatx4 acc[4][4] = {};

  const u16* gA0 = A + (size_t)(row0 + 32 * w + l15) * 1024 + 8 * lq;
  const u16* gA1 = gA0 + 16 * 1024;
  const u16* gB0 = Wt + (size_t)(col0 + 32 * w + l15) * 1024 + 8 * lq;
  const u16* gB1 = gB0 + 16 * 1024;
  int sbase = (2 * w) * 512;

  int afrag_off[4], bfrag_off[4];
#pragma unroll
  for (int i = 0; i < 4; ++i) {
    afrag_off[i] = (wr * 4 + i) * 512 + lq * 128 + l15 * 8;
    bfrag_off[i] = (wc * 4 + i) * 512 + lq * 128 + l15 * 8;
  }

  // prologue: stage tile 0 into buffer 0
  async_copy16(gA0, &As[0][sbase]);
  async_copy16(gA1, &As[0][sbase + 512]);
  async_copy16(gB0, &Bs[0][sbase]);
  async_copy16(gB1, &Bs[0][sbase + 512]);

  for (int it = 0; it < 32; ++it) {
    __syncthreads();                       // tile `it` resident (vmcnt drained)
    int nxt = it + 1;
    if (nxt < 32) {                        // prefetch overlaps MFMAs below
      int nb = nxt & 1, k0 = nxt * 32;
      async_copy16(gA0 + k0, &As[nb][sbase]);
      async_copy16(gA1 + k0, &As[nb][sbase + 512]);
      async_copy16(gB0 + k0, &Bs[nb][sbase]);
      async_copy16(gB1 + k0, &Bs[nb][sbase + 512]);
    }
    int cb = it & 1;
    short8v af[4], bf[4];
#pragma unroll
    for (int i = 0; i < 4; ++i) af[i] = *(const short8v*)(&As[cb][afrag_off[i]]);
#pragma unroll
    for (int i = 0; i < 4; ++i) bf[i] = *(const short8v*)(&Bs[cb][bfrag_off[i]]);
#pragma unroll
    for (int mi = 0; mi < 4; ++mi)
#pragma unroll
      for (int ni = 0; ni < 4; ++ni)
        acc[mi][ni] = __builtin_amdgcn_mfma_f32_16x16x32_bf16(
            af[mi], bf[ni], acc[mi][ni], 0, 0, 0);
  }

  int rowbase = row0 + wr * 64, colbase = col0 + wc * 64;
#pragma unroll
  for (int ni = 0; ni < 4; ++ni) {
    int col = colbase + ni * 16 + l15;
    float bcol = bias[col];
#pragma unroll
    for (int mi = 0; mi < 4; ++mi) {
      int rtop = rowbase + mi * 16 + lq * 4;
#pragma unroll
      for (int reg = 0; reg < 4; ++reg) {
        float vv = acc[mi][ni][reg] + bcol;
        if (RESID) vv += resid[(size_t)(rtop + reg) * nco + col];
        if (GELU) vv = 0.5f * vv * (1.f + erff(vv * 0.70710678118654752f));
        if (OUTBF16)
          ((u16*)Cv)[(size_t)(rtop + reg) * nco + col] = f2bf(vv);
        else
          ((float*)Cv)[(size_t)(rtop + reg) * nco + col] = vv;
      }
    }
  }
}

// ---------------- MFMA flash attention (packed qkv, stride 3072); out = z + attn ------
__global__ __launch_bounds__(256) void attention_kernel(
    const u16* __restrict__ qkv, const int* __restrict__ lengths,
    const float* __restrict__ zres, float* __restrict__ out) {
  const int LDQ = 3072;
  __shared__ u16 Vt[64 * VT_STRIDE];
  __shared__ u16 Pb[4][16 * 40];
  int hh = blockIdx.x & 1;
  int h = (blockIdx.x >> 1) & 15;
  int b = blockIdx.x >> 5;
  int tid = threadIdx.x;
  const size_t base = ((size_t)b * Sz) * LDQ + (size_t)h * DHEAD;
  const u16* qp = qkv + base;
  const u16* kp = qkv + base + 1024;
  const u16* vp = qkv + base + 2048;

  for (int idx = tid; idx < 256 * 16; idx += 256) {
    int key = idx >> 4, d4 = (idx & 15) * 4;
    uint2 vv;
    if (key < Sz) vv = *(const uint2*)(vp + (size_t)key * LDQ + d4);
    else { vv.x = 0u; vv.y = 0u; }
    Vt[(d4 + 0) * VT_STRIDE + key] = (u16)(vv.x & 0xFFFF);
    Vt[(d4 + 1) * VT_STRIDE + key] = (u16)(vv.x >> 16);
    Vt[(d4 + 2) * VT_STRIDE + key] = (u16)(vv.y & 0xFFFF);
    Vt[(d4 + 3) * VT_STRIDE + key] = (u16)(vv.y >> 16);
  }
  __syncthreads();

  int w = tid >> 6, lane = tid & 63;
  int qgroup = lane >> 4, qcol = lane & 15;
  int len_b = get_len(lengths, b);

  for (int qt = hh * 8 + w; qt < hh * 8 + 8 && qt < 15; qt += 4) {
    const u16* qrow = qp + (size_t)(qt * 16 + qcol) * LDQ;
    short8v aq0 = *(const short8v*)(qrow + qgroup * 8);
    short8v aq1 = *(const short8v*)(qrow + 32 + qgroup * 8);
    floatx4 o0 = {0.f, 0.f, 0.f, 0.f}, o1 = o0, o2 = o0, o3 = o0;
    float m_run[4] = {-1e30f, -1e30f, -1e30f, -1e30f};
    float l_run[4] = {0.f, 0.f, 0.f, 0.f};
    int nsteps = (qt + 2) >> 1;

    for (int st = 0; st < nsteps; ++st) {
      int t0 = 2 * st, t1 = 2 * st + 1;
      bool has1 = (t1 <= qt);
      floatx4 s0 = {0.f, 0.f, 0.f, 0.f};
      {
        const u16* kr = kp + (size_t)(t0 * 16 + qcol) * LDQ;
        short8v bk0 = *(const short8v*)(kr + qgroup * 8);
        short8v bk1 = *(const short8v*)(kr + 32 + qgroup * 8);
        s0 = __builtin_amdgcn_mfma_f32_16x16x32_bf16(aq0, bk0, s0, 0, 0, 0);
        s0 = __builtin_amdgcn_mfma_f32_16x16x32_bf16(aq1, bk1, s0, 0, 0, 0);
      }
      floatx4 s1 = {0.f, 0.f, 0.f, 0.f};
      if (has1) {
        const u16* kr = kp + (size_t)(t1 * 16 + qcol) * LDQ;
        short8v bk0 = *(const short8v*)(kr + qgroup * 8);
        short8v bk1 = *(const short8v*)(kr + 32 + qgroup * 8);
        s1 = __builtin_amdgcn_mfma_f32_16x16x32_bf16(aq0, bk0, s1, 0, 0, 0);
        s1 = __builtin_amdgcn_mfma_f32_16x16x32_bf16(aq1, bk1, s1, 0, 0, 0);
      }
      int kg0 = t0 * 16 + qcol, kg1 = t1 * 16 + qcol;
      float p0[4], p1[4];
#pragma unroll
      for (int rg = 0; rg < 4; ++rg) {
        int row_g = qt * 16 + qgroup * 4 + rg;
        float x0 = (kg0 <= row_g) ? s0[rg] * 0.03125f : -1e30f;
        float x1 = (has1 && kg1 <= row_g) ? s1[rg] * 0.03125f : -1e30f;
        float mx = fmaxf(x0, x1);
        mx = fmaxf(mx, __shfl_xor(mx, 1));
        mx = fmaxf(mx, __shfl_xor(mx, 2));
        mx = fmaxf(mx, __shfl_xor(mx, 4));
        mx = fmaxf(mx, __shfl_xor(mx, 8));
        float mnew = fmaxf(m_run[rg], mx);
        float alpha = __expf(m_run[rg] - mnew);
        float e0 = __expf(x0 - mnew);
        float e1 = __expf(x1 - mnew);
        float rs = e0 + e1;
        rs += __shfl_xor(rs, 1);
        rs += __shfl_xor(rs, 2);
        rs += __shfl_xor(rs, 4);
        rs += __shfl_xor(rs, 8);
        l_run[rg] = l_run[rg] * alpha + rs;
        m_run[rg] = mnew;
        o0[rg] *= alpha; o1[rg] *= alpha; o2[rg] *= alpha; o3[rg] *= alpha;
        p0[rg] = e0; p1[rg] = e1;
      }
#pragma unroll
      for (int rg = 0; rg < 4; ++rg) {
        int rl = qgroup * 4 + rg;
        Pb[w][rl * 40 + qcol] = f2bf(p0[rg]);
        Pb[w][rl * 40 + 16 + qcol] = f2bf(p1[rg]);
      }
      __asm__ volatile("s_waitcnt lgkmcnt(0)" ::: "memory");
      short8v pa = *(const short8v*)(&Pb[w][qcol * 40 + qgroup * 8]);
      int kb0 = st * 32 + qgroup * 8;
      short8v bv0 = *(const short8v*)(&Vt[(0 * 16 + qcol) * VT_STRIDE + kb0]);
      short8v bv1 = *(const short8v*)(&Vt[(1 * 16 + qcol) * VT_STRIDE + kb0]);
      short8v bv2 = *(const short8v*)(&Vt[(2 * 16 + qcol) * VT_STRIDE + kb0]);
      short8v bv3 = *(const short8v*)(&Vt[(3 * 16 + qcol) * VT_STRIDE + kb0]);
      o0 = __builtin_amdgcn_mfma_f32_16x16x32_bf16(pa, bv0, o0, 0, 0, 0);
      o1 = __builtin_amdgcn_mfma_f32_16x16x32_bf16(pa, bv1, o1, 0, 0, 0);
      o2 = __builtin_amdgcn_mfma_f32_16x16x32_bf16(pa, bv2, o2, 0, 0, 0);
      o3 = __builtin_amdgcn_mfma_f32_16x16x32_bf16(pa, bv3, o3, 0, 0, 0);
    }

#pragma unroll
    for (int rg = 0; rg < 4; ++rg) {
      int row_g = qt * 16 + qgroup * 4 + rg;
      float vmask = (row_g < len_b) ? (1.f / l_run[rg]) : 0.f;
      size_t ob = ((size_t)b * Sz + row_g) * Hz + (size_t)h * DHEAD + qcol;
      out[ob]      = zres[ob]      + o0[rg] * vmask;
      out[ob + 16] = zres[ob + 16] + o1[rg] * vmask;
      out[ob + 32] = zres[ob + 32] + o2[rg] * vmask;
      out[ob + 48] = zres[ob + 48] + o3[rg] * vmask;
    }
  }
}

// ---------------- LayerNorm of r (residual pre-added); writes z, z_bf ----------------
__global__ __launch_bounds__(256) void add_ln_kernel(
    float* __restrict__ z, u16* __restrict__ z_bf, const float* __restrict__ r,
    const float* __restrict__ gamma, const float* __restrict__ beta) {
  int bs = blockIdx.x, tid = threadIdx.x;
  size_t base = (size_t)bs * Hz;
  __shared__ float sred[256];
  float4 v4 = *(const float4*)(r + base + tid * 4);
  float sum = v4.x + v4.y + v4.z + v4.w;
  sred[tid] = sum; __syncthreads();
  for (int off = 128; off > 0; off >>= 1) {
    if (tid < off) sred[tid] += sred[tid + off];
    __syncthreads();
  }
  float mean = sred[0] * (1.f / Hz); __syncthreads();
  float dx = v4.x - mean, dy = v4.y - mean, dz = v4.z - mean, dw = v4.w - mean;
  sred[tid] = dx * dx + dy * dy + dz * dz + dw * dw; __syncthreads();
  for (int off = 128; off > 0; off >>= 1) {
    if (tid < off) sred[tid] += sred[tid + off];
    __syncthreads();
  }
  float rstd = rsqrtf(sred[0] * (1.f / Hz) + 1e-5f);
  float4 g4 = *(const float4*)(gamma + tid * 4);
  float4 b4 = *(const float4*)(beta + tid * 4);
  float4 o;
  o.x = dx * rstd * g4.x + b4.x;
  o.y = dy * rstd * g4.y + b4.y;
  o.z = dz * rstd * g4.z + b4.z;
  o.w = dw * rstd * g4.w + b4.w;
  *(float4*)(z + base + tid * 4) = o;
  uint2 pk;
  pk.x = (u32)f2bf(o.x) | ((u32)f2bf(o.y) << 16);
  pk.y = (u32)f2bf(o.z) | ((u32)f2bf(o.w) << 16);
  *(uint2*)(z_bf + base + tid * 4) = pk;
}

// ---------------- pool phase 1: pooled[b][h] = mean_s z[b][s][h] ----------------
__global__ __launch_bounds__(256) void pool1_kernel(
    const float* __restrict__ z, float* __restrict__ pooled) {
  int chunk = blockIdx.x, b = blockIdx.y, tid = threadIdx.x;
  int h = chunk * 128 + (tid & 127);
  int half = tid >> 7;
  __shared__ float sred[256];
  const float* zp = z + ((size_t)b * Sz + half * 120) * Hz + h;
  float s = 0.f;
  for (int i = 0; i < 120; ++i) s += zp[(size_t)i * Hz];
  sred[tid] = s; __syncthreads();
  if (tid < 128)
    pooled[(size_t)b * Hz + chunk * 128 + tid] =
        (sred[tid] + sred[tid + 128]) * (1.f / Sz);
}

// ---------------- pool phase 2: FC + softmax -> fp32 out ----------------
__global__ __launch_bounds__(256) void pool2_kernel(
    const float* __restrict__ pooled, const float* __restrict__ Wfc,
    const float* __restrict__ bfc, float* __restrict__ out) {
  int b = blockIdx.x, tid = threadIdx.x;
  __shared__ float red[256][4];
  float acc[4] = {0.f, 0.f, 0.f, 0.f};
#pragma unroll
  for (int j = 0; j < 4; ++j) {
    int hh = tid * 4 + j;
    float z2 = pooled[(size_t)b * Hz + hh];
#pragma unroll
    for (int c = 0; c < 4; ++c) acc[c] += z2 * Wfc[hh * 4 + c];
  }
#pragma unroll
  for (int c = 0; c < 4; ++c) red[tid][c] = acc[c];
  __syncthreads();
  for (int off = 128; off > 0; off >>= 1) {
    if (tid < off)
#pragma unroll
      for (int c = 0; c < 4; ++c) red[tid][c] += red[tid + off][c];
    __syncthreads();
  }
  if (tid == 0) {
    float lg[4], m = -1e30f;
#pragma unroll
    for (int c = 0; c < 4; ++c) { lg[c] = red[0][c] + bfc[c]; m = fmaxf(m, lg[c]); }
    float s = 0.f;
#pragma unroll
    for (int c = 0; c < 4; ++c) { lg[c] = expf(lg[c] - m); s += lg[c]; }
    float inv = 1.f / s;
#pragma unroll
    for (int c = 0; c < 4; ++c) out[b * 4 + c] = lg[c] * inv;
  }
}

extern "C" void kernel_launch(void* const* d_in, const int* in_sizes, int n_in,
                              void* d_out, int out_size, void* d_ws, size_t ws_size,
                              hipStream_t stream) {
  const float* x     = (const float*)d_in[0];
  const float* w_emb = (const float*)d_in[1];
  const float* p_emb = (const float*)d_in[2];
  const float* Wq = (const float*)d_in[3];
  const float* bq = (const float*)d_in[4];
  const float* Wk = (const float*)d_in[5];
  const float* bk = (const float*)d_in[6];
  const float* Wv = (const float*)d_in[7];
  const float* bv = (const float*)d_in[8];
  const float* W1 = (const float*)d_in[9];
  const float* b1 = (const float*)d_in[10];
  const float* W2 = (const float*)d_in[11];
  const float* b2 = (const float*)d_in[12];
  const float* ln1s = (const float*)d_in[13];
  const float* ln1b = (const float*)d_in[14];
  const float* ln2s = (const float*)d_in[15];
  const float* ln2b = (const float*)d_in[16];
  const float* Wfc  = (const float*)d_in[17];
  const float* bfc  = (const float*)d_in[18];
  const int* lengths = (const int*)d_in[19];
  float* out = (float*)d_out;

  const size_t BSH = (size_t)Bz * Sz * Hz;   // 7,864,320
  float* z    = (float*)d_ws;                // fp32 BSH
  float* ao   = z + BSH;                     // fp32 BSH (z+attn / z1+ff2)
  u16* z_bf   = (u16*)(ao + BSH);            // bf16 BSH
  u16* ffb    = z_bf + BSH;                  // bf16 BSH (FF1 out)
  u16* qkv    = ffb + BSH;                   // bf16 3*BSH
  u16* wt     = qkv + 3 * BSH;               // bf16 5M
  float* bqkv = (float*)(wt + 5 * 1024 * 1024);   // Lz*3072
  float* pooled = bqkv + Lz * 3072;          // 32*1024 fp32

  embed_kernel<<<Bz * Sz, 256, 0, stream>>>(x, w_emb, p_emb, lengths, z, z_bf);
  bias_concat<<<Lz * 3072 / 256, 256, 0, stream>>>(bq, bk, bv, bqkv);

  for (int i = 0; i < Lz; ++i) {
    size_t wo = (size_t)i * Hz * Hz, bo = (size_t)i * Hz;
    WconvArgs wa;
    wa.src[0] = Wq + wo; wa.src[1] = Wk + wo; wa.src[2] = Wv + wo;
    wa.src[3] = W1 + wo; wa.src[4] = W2 + wo;
    wa.dst[0] = wt;                     wa.dst[1] = wt + 1024 * 1024;
    wa.dst[2] = wt + 2 * 1024 * 1024;   wa.dst[3] = wt + 3 * 1024 * 1024;
    wa.dst[4] = wt + 4 * 1024 * 1024;
    wconv5<<<dim3(32, 32, 5), 256, 0, stream>>>(wa);

    gemm_mfma<true, false, false><<<60 * 24, 256, 0, stream>>>(
        z_bf, wt, bqkv + (size_t)i * 3072, nullptr, qkv, 3072);
    attention_kernel<<<Bz * NHEADS * 2, 256, 0, stream>>>(qkv, lengths, z, ao);
    add_ln_kernel<<<Bz * Sz, 256, 0, stream>>>(z, z_bf, ao, ln1s + bo, ln1b + bo);
    gemm_mfma<true, true, false><<<60 * 8, 256, 0, stream>>>(
        z_bf, wt + 3 * 1024 * 1024, b1 + bo, nullptr, ffb, 1024);
    gemm_mfma<false, false, true><<<60 * 8, 256, 0, stream>>>(
        ffb, wt + 4 * 1024 * 1024, b2 + bo, z, ao, 1024);
    add_ln_kernel<<<Bz * Sz, 256, 0, stream>>>(z, z_bf, ao, ln2s + bo, ln2b + bo);
  }
  pool1_kernel<<<dim3(8, Bz), 256, 0, stream>>>(z, pooled);
  pool2_kernel<<<Bz, 256, 0, stream>>>(pooled, Wfc, bfc, out);
}

// Round 10
// 2230.777 us; speedup vs baseline: 8.7862x; 1.0039x over previous
//
#include <hip/hip_runtime.h>
#include <hip/hip_bf16.h>

#define Bz 32
#define Sz 240
#define Hz 1024
#define Lz 8
#define NHEADS 16
#define NVOCAB 48
#define DHEAD 64
#define VT_STRIDE 264

typedef unsigned short u16;
typedef unsigned int u32;
typedef __attribute__((ext_vector_type(8))) short short8v;
typedef __attribute__((ext_vector_type(4))) float floatx4;

__device__ __forceinline__ int get_len(const int* __restrict__ L, int b) {
  return (L[1] == 0) ? L[2 * b] : L[b];
}
__device__ __forceinline__ u16 f2bf(float f) {  // RNE fp32->bf16
  u32 u = __float_as_uint(f);
  return (u16)((u + 0x7FFFu + ((u >> 16) & 1u)) >> 16);
}
__device__ __forceinline__ float bf2f(u16 s) {
  return __uint_as_float(((u32)s) << 16);
}
__device__ __forceinline__ void async_copy16(const u16* g, u16* l) {
  __builtin_amdgcn_global_load_lds(
      (const __attribute__((address_space(1))) u32*)g,
      (__attribute__((address_space(3))) u32*)l, 16, 0, 0);
}

// ---------------- embedding ----------------
__global__ __launch_bounds__(256) void embed_kernel(
    const float* __restrict__ x, const float* __restrict__ w_emb,
    const float* __restrict__ p_emb, const int* __restrict__ lengths,
    float* __restrict__ z, u16* __restrict__ z_bf) {
  int bs = blockIdx.x;
  int b = bs / Sz, s = bs % Sz;
  __shared__ int stok;
  if (threadIdx.x == 0) {
    const float* xr = x + (size_t)bs * NVOCAB;
    float best = xr[0]; int bi = 0;
    for (int j = 1; j < NVOCAB; ++j) {
      float v = xr[j];
      if (v > best) { best = v; bi = j; }
    }
    stok = bi;
  }
  __syncthreads();
  int tok = stok;
  float valid = (s < get_len(lengths, b)) ? 1.f : 0.f;
  const float* we = w_emb + (size_t)tok * Hz;
  const float* pe = p_emb + (size_t)s * Hz;
  size_t base = (size_t)bs * Hz;
  for (int h = threadIdx.x; h < Hz; h += blockDim.x) {
    float v = we[h] * valid + pe[h];
    z[base + h] = v;
    z_bf[base + h] = f2bf(v);
  }
}

// ---------------- bias concat: [L][3072] = bq|bk|bv ----------------
__global__ __launch_bounds__(256) void bias_concat(
    const float* __restrict__ bq, const float* __restrict__ bk,
    const float* __restrict__ bv, float* __restrict__ dst) {
  int i = blockIdx.x * 256 + threadIdx.x;
  int l = i / 3072, c = i % 3072;
  float v = (c < 1024) ? bq[l * 1024 + c]
          : (c < 2048) ? bk[l * 1024 + c - 1024]
                       : bv[l * 1024 + c - 2048];
  dst[i] = v;
}

// ---------------- weight convert+transpose, 5 matrices per layer ----------------
struct WconvArgs { const float* src[5]; u16* dst[5]; };
__global__ __launch_bounds__(256) void wconv5(WconvArgs a) {
  __shared__ u16 T[32][33];
  const float* W = a.src[blockIdx.z];
  u16* wt = a.dst[blockIdx.z];
  int bi = blockIdx.y, bj = blockIdx.x;
  int r = threadIdx.x >> 3, c4 = (threadIdx.x & 7) * 4;
  float4 w4 = *(const float4*)(W + (size_t)(bi * 32 + r) * Hz + bj * 32 + c4);
  T[r][c4 + 0] = f2bf(w4.x); T[r][c4 + 1] = f2bf(w4.y);
  T[r][c4 + 2] = f2bf(w4.z); T[r][c4 + 3] = f2bf(w4.w);
  __syncthreads();
  u32 lo = (u32)T[c4 + 0][r] | ((u32)T[c4 + 1][r] << 16);
  u32 hi = (u32)T[c4 + 2][r] | ((u32)T[c4 + 3][r] << 16);
  uint2 val; val.x = lo; val.y = hi;
  *(uint2*)(wt + (size_t)(bj * 32 + r) * Hz + bi * 32 + c4) = val;
}

// ---------------- MFMA GEMM, single-buffer BK=64 ----------------
// C[7680,nco] = A(bf16)[7680,1024] @ Wt[nco,1024]^T + bias (+resid)
// 128x128 tile, BK=64 (32 KB LDS), 16 iters -> half the barrier drains of BK=32;
// 32 MFMAs amortize each vmcnt(0)+barrier. k-ascending: bit-identical results.
template <bool OUTBF16, bool GELU, bool RESID>
__global__ __launch_bounds__(256) void gemm_mfma(
    const u16* __restrict__ A, const u16* __restrict__ Wt,
    const float* __restrict__ bias, const float* __restrict__ resid,
    void* __restrict__ Cv, int nco) {
  __shared__ u16 As[8192];   // [ktile(2)][sub(8)][kchunk(4)][row(16)][8]
  __shared__ u16 Bs[8192];
  int tid = threadIdx.x;
  int xt = nco >> 7;
  int id = blockIdx.x;
  int per = xt << 3;
  int g = id / per;
  int rr = id - g * per;
  int ys = 60 - (g << 3); ys = ys > 8 ? 8 : ys;
  int row0 = ((g << 3) + rr % ys) * 128;
  int col0 = (rr / ys) * 128;

  int w = tid >> 6, lane = tid & 63;
  int l15 = lane & 15, lq = lane >> 4;
  int wr = w >> 1, wc = w & 1;
  floatx4 acc[4][4] = {};

  const u16* gA0 = A + (size_t)(row0 + 32 * w + l15) * 1024 + 8 * lq;
  const u16* gA1 = gA0 + 16 * 1024;
  const u16* gB0 = Wt + (size_t)(col0 + 32 * w + l15) * 1024 + 8 * lq;
  const u16* gB1 = gB0 + 16 * 1024;
  int sbase = (2 * w) * 512;

  int afrag_off[4], bfrag_off[4];
#pragma unroll
  for (int i = 0; i < 4; ++i) {
    afrag_off[i] = (wr * 4 + i) * 512 + lq * 128 + l15 * 8;
    bfrag_off[i] = (wc * 4 + i) * 512 + lq * 128 + l15 * 8;
  }

  for (int k0 = 0; k0 < 1024; k0 += 64) {
    async_copy16(gA0 + k0,      &As[sbase]);
    async_copy16(gA1 + k0,      &As[sbase + 512]);
    async_copy16(gA0 + k0 + 32, &As[4096 + sbase]);
    async_copy16(gA1 + k0 + 32, &As[4096 + sbase + 512]);
    async_copy16(gB0 + k0,      &Bs[sbase]);
    async_copy16(gB1 + k0,      &Bs[sbase + 512]);
    async_copy16(gB0 + k0 + 32, &Bs[4096 + sbase]);
    async_copy16(gB1 + k0 + 32, &Bs[4096 + sbase + 512]);
    __syncthreads();
#pragma unroll
    for (int kt = 0; kt < 2; ++kt) {
      short8v af[4], bf[4];
#pragma unroll
      for (int i = 0; i < 4; ++i)
        af[i] = *(const short8v*)(&As[kt * 4096 + afrag_off[i]]);
#pragma unroll
      for (int i = 0; i < 4; ++i)
        bf[i] = *(const short8v*)(&Bs[kt * 4096 + bfrag_off[i]]);
#pragma unroll
      for (int mi = 0; mi < 4; ++mi)
#pragma unroll
        for (int ni = 0; ni < 4; ++ni)
          acc[mi][ni] = __builtin_amdgcn_mfma_f32_16x16x32_bf16(
              af[mi], bf[ni], acc[mi][ni], 0, 0, 0);
    }
    __syncthreads();
  }

  int rowbase = row0 + wr * 64, colbase = col0 + wc * 64;
#pragma unroll
  for (int ni = 0; ni < 4; ++ni) {
    int col = colbase + ni * 16 + l15;
    float bcol = bias[col];
#pragma unroll
    for (int mi = 0; mi < 4; ++mi) {
      int rtop = rowbase + mi * 16 + lq * 4;
#pragma unroll
      for (int reg = 0; reg < 4; ++reg) {
        float vv = acc[mi][ni][reg] + bcol;
        if (RESID) vv += resid[(size_t)(rtop + reg) * nco + col];
        if (GELU) vv = 0.5f * vv * (1.f + erff(vv * 0.70710678118654752f));
        if (OUTBF16)
          ((u16*)Cv)[(size_t)(rtop + reg) * nco + col] = f2bf(vv);
        else
          ((float*)Cv)[(size_t)(rtop + reg) * nco + col] = vv;
      }
    }
  }
}

// ---------------- MFMA flash attention (packed qkv, stride 3072); out = z + attn ------
__global__ __launch_bounds__(256) void attention_kernel(
    const u16* __restrict__ qkv, const int* __restrict__ lengths,
    const float* __restrict__ zres, float* __restrict__ out) {
  const int LDQ = 3072;
  __shared__ u16 Vt[64 * VT_STRIDE];
  __shared__ u16 Pb[4][16 * 40];
  int hh = blockIdx.x & 1;
  int h = (blockIdx.x >> 1) & 15;
  int b = blockIdx.x >> 5;
  int tid = threadIdx.x;
  const size_t base = ((size_t)b * Sz) * LDQ + (size_t)h * DHEAD;
  const u16* qp = qkv + base;
  const u16* kp = qkv + base + 1024;
  const u16* vp = qkv + base + 2048;

  for (int idx = tid; idx < 256 * 16; idx += 256) {
    int key = idx >> 4, d4 = (idx & 15) * 4;
    uint2 vv;
    if (key < Sz) vv = *(const uint2*)(vp + (size_t)key * LDQ + d4);
    else { vv.x = 0u; vv.y = 0u; }
    Vt[(d4 + 0) * VT_STRIDE + key] = (u16)(vv.x & 0xFFFF);
    Vt[(d4 + 1) * VT_STRIDE + key] = (u16)(vv.x >> 16);
    Vt[(d4 + 2) * VT_STRIDE + key] = (u16)(vv.y & 0xFFFF);
    Vt[(d4 + 3) * VT_STRIDE + key] = (u16)(vv.y >> 16);
  }
  __syncthreads();

  int w = tid >> 6, lane = tid & 63;
  int qgroup = lane >> 4, qcol = lane & 15;
  int len_b = get_len(lengths, b);

  for (int qt = hh * 8 + w; qt < hh * 8 + 8 && qt < 15; qt += 4) {
    const u16* qrow = qp + (size_t)(qt * 16 + qcol) * LDQ;
    short8v aq0 = *(const short8v*)(qrow + qgroup * 8);
    short8v aq1 = *(const short8v*)(qrow + 32 + qgroup * 8);
    floatx4 o0 = {0.f, 0.f, 0.f, 0.f}, o1 = o0, o2 = o0, o3 = o0;
    float m_run[4] = {-1e30f, -1e30f, -1e30f, -1e30f};
    float l_run[4] = {0.f, 0.f, 0.f, 0.f};
    int nsteps = (qt + 2) >> 1;

    for (int st = 0; st < nsteps; ++st) {
      int t0 = 2 * st, t1 = 2 * st + 1;
      bool has1 = (t1 <= qt);
      floatx4 s0 = {0.f, 0.f, 0.f, 0.f};
      {
        const u16* kr = kp + (size_t)(t0 * 16 + qcol) * LDQ;
        short8v bk0 = *(const short8v*)(kr + qgroup * 8);
        short8v bk1 = *(const short8v*)(kr + 32 + qgroup * 8);
        s0 = __builtin_amdgcn_mfma_f32_16x16x32_bf16(aq0, bk0, s0, 0, 0, 0);
        s0 = __builtin_amdgcn_mfma_f32_16x16x32_bf16(aq1, bk1, s0, 0, 0, 0);
      }
      floatx4 s1 = {0.f, 0.f, 0.f, 0.f};
      if (has1) {
        const u16* kr = kp + (size_t)(t1 * 16 + qcol) * LDQ;
        short8v bk0 = *(const short8v*)(kr + qgroup * 8);
        short8v bk1 = *(const short8v*)(kr + 32 + qgroup * 8);
        s1 = __builtin_amdgcn_mfma_f32_16x16x32_bf16(aq0, bk0, s1, 0, 0, 0);
        s1 = __builtin_amdgcn_mfma_f32_16x16x32_bf16(aq1, bk1, s1, 0, 0, 0);
      }
      int kg0 = t0 * 16 + qcol, kg1 = t1 * 16 + qcol;
      float p0[4], p1[4];
#pragma unroll
      for (int rg = 0; rg < 4; ++rg) {
        int row_g = qt * 16 + qgroup * 4 + rg;
        float x0 = (kg0 <= row_g) ? s0[rg] * 0.03125f : -1e30f;
        float x1 = (has1 && kg1 <= row_g) ? s1[rg] * 0.03125f : -1e30f;
        float mx = fmaxf(x0, x1);
        mx = fmaxf(mx, __shfl_xor(mx, 1));
        mx = fmaxf(mx, __shfl_xor(mx, 2));
        mx = fmaxf(mx, __shfl_xor(mx, 4));
        mx = fmaxf(mx, __shfl_xor(mx, 8));
        float mnew = fmaxf(m_run[rg], mx);
        float alpha = __expf(m_run[rg] - mnew);
        float e0 = __expf(x0 - mnew);
        float e1 = __expf(x1 - mnew);
        float rs = e0 + e1;
        rs += __shfl_xor(rs, 1);
        rs += __shfl_xor(rs, 2);
        rs += __shfl_xor(rs, 4);
        rs += __shfl_xor(rs, 8);
        l_run[rg] = l_run[rg] * alpha + rs;
        m_run[rg] = mnew;
        o0[rg] *= alpha; o1[rg] *= alpha; o2[rg] *= alpha; o3[rg] *= alpha;
        p0[rg] = e0; p1[rg] = e1;
      }
#pragma unroll
      for (int rg = 0; rg < 4; ++rg) {
        int rl = qgroup * 4 + rg;
        Pb[w][rl * 40 + qcol] = f2bf(p0[rg]);
        Pb[w][rl * 40 + 16 + qcol] = f2bf(p1[rg]);
      }
      __asm__ volatile("s_waitcnt lgkmcnt(0)" ::: "memory");
      short8v pa = *(const short8v*)(&Pb[w][qcol * 40 + qgroup * 8]);
      int kb0 = st * 32 + qgroup * 8;
      short8v bv0 = *(const short8v*)(&Vt[(0 * 16 + qcol) * VT_STRIDE + kb0]);
      short8v bv1 = *(const short8v*)(&Vt[(1 * 16 + qcol) * VT_STRIDE + kb0]);
      short8v bv2 = *(const short8v*)(&Vt[(2 * 16 + qcol) * VT_STRIDE + kb0]);
      short8v bv3 = *(const short8v*)(&Vt[(3 * 16 + qcol) * VT_STRIDE + kb0]);
      o0 = __builtin_amdgcn_mfma_f32_16x16x32_bf16(pa, bv0, o0, 0, 0, 0);
      o1 = __builtin_amdgcn_mfma_f32_16x16x32_bf16(pa, bv1, o1, 0, 0, 0);
      o2 = __builtin_amdgcn_mfma_f32_16x16x32_bf16(pa, bv2, o2, 0, 0, 0);
      o3 = __builtin_amdgcn_mfma_f32_16x16x32_bf16(pa, bv3, o3, 0, 0, 0);
    }

#pragma unroll
    for (int rg = 0; rg < 4; ++rg) {
      int row_g = qt * 16 + qgroup * 4 + rg;
      float vmask = (row_g < len_b) ? (1.f / l_run[rg]) : 0.f;
      size_t ob = ((size_t)b * Sz + row_g) * Hz + (size_t)h * DHEAD + qcol;
      out[ob]      = zres[ob]      + o0[rg] * vmask;
      out[ob + 16] = zres[ob + 16] + o1[rg] * vmask;
      out[ob + 32] = zres[ob + 32] + o2[rg] * vmask;
      out[ob + 48] = zres[ob + 48] + o3[rg] * vmask;
    }
  }
}

// ---------------- LayerNorm of r (residual pre-added); writes z, z_bf ----------------
__global__ __launch_bounds__(256) void add_ln_kernel(
    float* __restrict__ z, u16* __restrict__ z_bf, const float* __restrict__ r,
    const float* __restrict__ gamma, const float* __restrict__ beta) {
  int bs = blockIdx.x, tid = threadIdx.x;
  size_t base = (size_t)bs * Hz;
  __shared__ float sred[256];
  float4 v4 = *(const float4*)(r + base + tid * 4);
  float sum = v4.x + v4.y + v4.z + v4.w;
  sred[tid] = sum; __syncthreads();
  for (int off = 128; off > 0; off >>= 1) {
    if (tid < off) sred[tid] += sred[tid + off];
    __syncthreads();
  }
  float mean = sred[0] * (1.f / Hz); __syncthreads();
  float dx = v4.x - mean, dy = v4.y - mean, dz = v4.z - mean, dw = v4.w - mean;
  sred[tid] = dx * dx + dy * dy + dz * dz + dw * dw; __syncthreads();
  for (int off = 128; off > 0; off >>= 1) {
    if (tid < off) sred[tid] += sred[tid + off];
    __syncthreads();
  }
  float rstd = rsqrtf(sred[0] * (1.f / Hz) + 1e-5f);
  float4 g4 = *(const float4*)(gamma + tid * 4);
  float4 b4 = *(const float4*)(beta + tid * 4);
  float4 o;
  o.x = dx * rstd * g4.x + b4.x;
  o.y = dy * rstd * g4.y + b4.y;
  o.z = dz * rstd * g4.z + b4.z;
  o.w = dw * rstd * g4.w + b4.w;
  *(float4*)(z + base + tid * 4) = o;
  uint2 pk;
  pk.x = (u32)f2bf(o.x) | ((u32)f2bf(o.y) << 16);
  pk.y = (u32)f2bf(o.z) | ((u32)f2bf(o.w) << 16);
  *(uint2*)(z_bf + base + tid * 4) = pk;
}

// ---------------- pool phase 1 ----------------
__global__ __launch_bounds__(256) void pool1_kernel(
    const float* __restrict__ z, float* __restrict__ pooled) {
  int chunk = blockIdx.x, b = blockIdx.y, tid = threadIdx.x;
  int h = chunk * 128 + (tid & 127);
  int half = tid >> 7;
  __shared__ float sred[256];
  const float* zp = z + ((size_t)b * Sz + half * 120) * Hz + h;
  float s = 0.f;
  for (int i = 0; i < 120; ++i) s += zp[(size_t)i * Hz];
  sred[tid] = s; __syncthreads();
  if (tid < 128)
    pooled[(size_t)b * Hz + chunk * 128 + tid] =
        (sred[tid] + sred[tid + 128]) * (1.f / Sz);
}

// ---------------- pool phase 2: FC + softmax -> fp32 out ----------------
__global__ __launch_bounds__(256) void pool2_kernel(
    const float* __restrict__ pooled, const float* __restrict__ Wfc,
    const float* __restrict__ bfc, float* __restrict__ out) {
  int b = blockIdx.x, tid = threadIdx.x;
  __shared__ float red[256][4];
  float acc[4] = {0.f, 0.f, 0.f, 0.f};
#pragma unroll
  for (int j = 0; j < 4; ++j) {
    int hh = tid * 4 + j;
    float z2 = pooled[(size_t)b * Hz + hh];
#pragma unroll
    for (int c = 0; c < 4; ++c) acc[c] += z2 * Wfc[hh * 4 + c];
  }
#pragma unroll
  for (int c = 0; c < 4; ++c) red[tid][c] = acc[c];
  __syncthreads();
  for (int off = 128; off > 0; off >>= 1) {
    if (tid < off)
#pragma unroll
      for (int c = 0; c < 4; ++c) red[tid][c] += red[tid + off][c];
    __syncthreads();
  }
  if (tid == 0) {
    float lg[4], m = -1e30f;
#pragma unroll
    for (int c = 0; c < 4; ++c) { lg[c] = red[0][c] + bfc[c]; m = fmaxf(m, lg[c]); }
    float s = 0.f;
#pragma unroll
    for (int c = 0; c < 4; ++c) { lg[c] = expf(lg[c] - m); s += lg[c]; }
    float inv = 1.f / s;
#pragma unroll
    for (int c = 0; c < 4; ++c) out[b * 4 + c] = lg[c] * inv;
  }
}

extern "C" void kernel_launch(void* const* d_in, const int* in_sizes, int n_in,
                              void* d_out, int out_size, void* d_ws, size_t ws_size,
                              hipStream_t stream) {
  const float* x     = (const float*)d_in[0];
  const float* w_emb = (const float*)d_in[1];
  const float* p_emb = (const float*)d_in[2];
  const float* Wq = (const float*)d_in[3];
  const float* bq = (const float*)d_in[4];
  const float* Wk = (const float*)d_in[5];
  const float* bk = (const float*)d_in[6];
  const float* Wv = (const float*)d_in[7];
  const float* bv = (const float*)d_in[8];
  const float* W1 = (const float*)d_in[9];
  const float* b1 = (const float*)d_in[10];
  const float* W2 = (const float*)d_in[11];
  const float* b2 = (const float*)d_in[12];
  const float* ln1s = (const float*)d_in[13];
  const float* ln1b = (const float*)d_in[14];
  const float* ln2s = (const float*)d_in[15];
  const float* ln2b = (const float*)d_in[16];
  const float* Wfc  = (const float*)d_in[17];
  const float* bfc  = (const float*)d_in[18];
  const int* lengths = (const int*)d_in[19];
  float* out = (float*)d_out;

  const size_t BSH = (size_t)Bz * Sz * Hz;   // 7,864,320
  float* z    = (float*)d_ws;                // fp32 BSH
  float* ao   = z + BSH;                     // fp32 BSH (z+attn / z1+ff2)
  u16* z_bf   = (u16*)(ao + BSH);            // bf16 BSH
  u16* ffb    = z_bf + BSH;                  // bf16 BSH (FF1 out)
  u16* qkv    = ffb + BSH;                   // bf16 3*BSH
  u16* wt     = qkv + 3 * BSH;               // bf16 5M
  float* bqkv = (float*)(wt + 5 * 1024 * 1024);   // Lz*3072
  float* pooled = bqkv + Lz * 3072;          // 32*1024 fp32

  embed_kernel<<<Bz * Sz, 256, 0, stream>>>(x, w_emb, p_emb, lengths, z, z_bf);
  bias_concat<<<Lz * 3072 / 256, 256, 0, stream>>>(bq, bk, bv, bqkv);

  for (int i = 0; i < Lz; ++i) {
    size_t wo = (size_t)i * Hz * Hz, bo = (size_t)i * Hz;
    WconvArgs wa;
    wa.src[0] = Wq + wo; wa.src[1] = Wk + wo; wa.src[2] = Wv + wo;
    wa.src[3] = W1 + wo; wa.src[4] = W2 + wo;
    wa.dst[0] = wt;                     wa.dst[1] = wt + 1024 * 1024;
    wa.dst[2] = wt + 2 * 1024 * 1024;   wa.dst[3] = wt + 3 * 1024 * 1024;
    wa.dst[4] = wt + 4 * 1024 * 1024;
    wconv5<<<dim3(32, 32, 5), 256, 0, stream>>>(wa);

    gemm_mfma<true, false, false><<<60 * 24, 256, 0, stream>>>(
        z_bf, wt, bqkv + (size_t)i * 3072, nullptr, qkv, 3072);
    attention_kernel<<<Bz * NHEADS * 2, 256, 0, stream>>>(qkv, lengths, z, ao);
    add_ln_kernel<<<Bz * Sz, 256, 0, stream>>>(z, z_bf, ao, ln1s + bo, ln1b + bo);
    gemm_mfma<true, true, false><<<60 * 8, 256, 0, stream>>>(
        z_bf, wt + 3 * 1024 * 1024, b1 + bo, nullptr, ffb, 1024);
    gemm_mfma<false, false, true><<<60 * 8, 256, 0, stream>>>(
        ffb, wt + 4 * 1024 * 1024, b2 + bo, z, ao, 1024);
    add_ln_kernel<<<Bz * Sz, 256, 0, stream>>>(z, z_bf, ao, ln2s + bo, ln2b + bo);
  }
  pool1_kernel<<<dim3(8, Bz), 256, 0, stream>>>(z, pooled);
  pool2_kernel<<<Bz, 256, 0, stream>>>(pooled, Wfc, bfc, out);
}